// Round 10
// baseline (75.314 us; speedup 1.0000x reference)
//
#include <hip/hip_runtime.h>

#define BB 8
#define TT_DIM 128
#define SS 512
#define DD 512
#define TANH_SCALE 2.885390081777927f   // 2*log2(e)
#define LOG2E 1.4426950408889634f

typedef unsigned short u16;
typedef short short8 __attribute__((ext_vector_type(8)));
typedef short short4v __attribute__((ext_vector_type(4)));
typedef float f32x4 __attribute__((ext_vector_type(4)));

__device__ __forceinline__ u16 f2bf(float f) {
  union { float f; unsigned u; } v; v.f = f;
  return (u16)((v.u + 0x7FFFu + ((v.u >> 16) & 1u)) >> 16);
}

// ---------------------------------------------------------------------------
// prep: bx<32  -> W transposes to bf16 Wt[n][k] (4 matrices, 8 blocks each)
//       bx>=32 -> straight fp32->bf16 cvt of output (first) then context.
// ---------------------------------------------------------------------------
__global__ __launch_bounds__(256) void prep_kernel(
    const float* __restrict__ output, const float* __restrict__ context,
    const float* __restrict__ dec_w, const float* __restrict__ attn_w,
    const float* __restrict__ out_w,
    u16* __restrict__ output_bf, u16* __restrict__ context_bf,
    u16* __restrict__ Wdt, u16* __restrict__ Wat,
    u16* __restrict__ Wot1t, u16* __restrict__ Wot2t) {
  int bx = blockIdx.x, t = threadIdx.x;
  if (bx < 32) {
    int w = bx >> 3;                 // which W
    int n0 = (bx & 7) * 64;
    const float* src = w == 0 ? dec_w : w == 1 ? attn_w
                     : w == 2 ? out_w : out_w + 512 * 512;
    u16* dst = w == 0 ? Wdt : w == 1 ? Wat : w == 2 ? Wot1t : Wot2t;
    int n = n0 + (t & 63);
    int kg = (t >> 6) * 8;
    for (int p = 0; p < 16; ++p) {
      int kk = p * 32 + kg;
      short8 o;
#pragma unroll
      for (int i = 0; i < 8; ++i)
        o[i] = (short)f2bf(src[(size_t)(kk + i) * 512 + n]);   // coalesced over n
      *(short8*)&dst[(size_t)n * 512 + kk] = o;
    }
  } else {
    const int N4_OUT = BB * TT_DIM * DD / 4;       // 131072
    const int N4_ALL = N4_OUT + BB * SS * DD / 4;  // 1179648
    int stride = (gridDim.x - 32) * 256;
    for (int i = (bx - 32) * 256 + t; i < N4_ALL; i += stride) {
      const f32x4* sp; short4v* dp; int j;
      if (i < N4_OUT) { sp = (const f32x4*)output;  dp = (short4v*)output_bf;  j = i; }
      else            { sp = (const f32x4*)context; dp = (short4v*)context_bf; j = i - N4_OUT; }
      f32x4 v = sp[j];
      short4v o;
      o[0] = (short)f2bf(v[0]); o[1] = (short)f2bf(v[1]);
      o[2] = (short)f2bf(v[2]); o[3] = (short)f2bf(v[3]);
      dp[j] = o;
    }
  }
}

// ---------------------------------------------------------------------------
// 64x64 MFMA GEMM body, ALL-bf16 inputs: A[m][k] bf16, Bt[n][k] bf16.
// Staging = contiguous short8 loads only. K=512.
// epi=1: exp(2x).  omode: 0 plain f32 | 1 packed^T f32 (Ftp) | 2 ^T bf16 (Ht)
// ---------------------------------------------------------------------------
__device__ __forceinline__ void gemm64_body(
    const u16* __restrict__ A, const u16* __restrict__ Bt,
    const float* __restrict__ bias, void* __restrict__ Y,
    int m0, int n0, int epi, int omode) {
  __shared__ u16 As[64][40];
  __shared__ u16 Bs[64][40];
  int t = threadIdx.x;
  int lane = t & 63, wid = t >> 6, wm = wid >> 1, wn = wid & 1;
  int ar = t >> 2, ac = (t & 3) * 8;
  int bn = t & 63, bk0 = (t >> 6) * 8;
  int fr = lane & 15, fh = (lane >> 4) * 8;

  const f32x4 fzero = {0.f, 0.f, 0.f, 0.f};
  f32x4 acc[2][2];
#pragma unroll
  for (int i = 0; i < 2; ++i)
#pragma unroll
    for (int j = 0; j < 2; ++j) acc[i][j] = fzero;

  short8 av, bv;
  auto loadA = [&](int k0) {
    av = *(const short8*)(A + (size_t)(m0 + ar) * 512 + k0 + ac);
  };
  auto loadB = [&](int k0) {
    bv = *(const short8*)(Bt + (size_t)(n0 + bn) * 512 + k0 + bk0);
  };

  loadA(0); loadB(0);
  for (int k0 = 0; k0 < 512; k0 += 32) {
    if (k0) __syncthreads();
    *(short8*)&As[ar][ac] = av;
    *(short8*)&Bs[bn][bk0] = bv;
    __syncthreads();
    short8 a0 = *(const short8*)&As[wm * 32 + fr][fh];
    short8 a1 = *(const short8*)&As[wm * 32 + 16 + fr][fh];
    short8 b0 = *(const short8*)&Bs[wn * 32 + fr][fh];
    short8 b1 = *(const short8*)&Bs[wn * 32 + 16 + fr][fh];
    if (k0 + 32 < 512) { loadA(k0 + 32); loadB(k0 + 32); }
    acc[0][0] = __builtin_amdgcn_mfma_f32_16x16x32_bf16(a0, b0, acc[0][0], 0, 0, 0);
    acc[0][1] = __builtin_amdgcn_mfma_f32_16x16x32_bf16(a0, b1, acc[0][1], 0, 0, 0);
    acc[1][0] = __builtin_amdgcn_mfma_f32_16x16x32_bf16(a1, b0, acc[1][0], 0, 0, 0);
    acc[1][1] = __builtin_amdgcn_mfma_f32_16x16x32_bf16(a1, b1, acc[1][1], 0, 0, 0);
  }

  // C/D layout (m89): col = lane&15, row = (lane>>4)*4 + j
#pragma unroll
  for (int qa = 0; qa < 2; ++qa) {
    int rbase = wm * 32 + qa * 16 + ((lane >> 4) << 2);
#pragma unroll
    for (int qn = 0; qn < 2; ++qn) {
      int col = n0 + wn * 32 + qn * 16 + (lane & 15);
      float bvs = bias ? bias[col] : 0.0f;
      f32x4 v4;
#pragma unroll
      for (int j = 0; j < 4; ++j) {
        float v = acc[qa][qn][j] + bvs;
        if (epi) v = __builtin_amdgcn_exp2f(v * TANH_SCALE);
        v4[j] = v;
      }
      int bb = m0 >> 9;
      int srow = (m0 & 511) + rbase;
      if (omode == 1) {          // packed transpose fp32 (Ftp[b][d>>3][s][d&7])
        float* Yf = (float*)Y;
        size_t base = ((size_t)bb * 64 + (col >> 3)) * 4096 + (size_t)(col & 7);
#pragma unroll
        for (int j = 0; j < 4; ++j)
          Yf[base + (size_t)(srow + j) * 8] = v4[j];
      } else if (omode == 2) {   // transpose bf16 (Ht[b][col][srow])
        u16* Yh = (u16*)Y;
        short4v o;
#pragma unroll
        for (int j = 0; j < 4; ++j) o[j] = (short)f2bf(v4[j]);
        *(short4v*)&Yh[((size_t)bb * 512 + col) * 512 + srow] = o;
      } else {                   // plain fp32
        float* Yf = (float*)Y;
#pragma unroll
        for (int j = 0; j < 4; ++j)
          Yf[(size_t)(m0 + rbase + j) * 512 + col] = v4[j];
      }
    }
  }
}

// blocks [0,16):    E  = exp(2*(output@dec_w+dec_b))          [1024,512]
// blocks [16,80):   Ftp= exp(2*(context@attn_w+attn_b)) packed^T
// blocks [80,96):   G  = output@out_w[512:] + out_b           [1024,512]
// blocks [96,160):  Ht = (context@out_w[:512])^T bf16         [8][512d][512s]
__global__ __launch_bounds__(256) void ef_gemm(
    const u16* __restrict__ output_bf, const u16* __restrict__ context_bf,
    const u16* __restrict__ Wdt, const u16* __restrict__ Wat,
    const u16* __restrict__ Wot1t, const u16* __restrict__ Wot2t,
    const float* __restrict__ dec_b, const float* __restrict__ attn_b,
    const float* __restrict__ out_b,
    float* __restrict__ E, float* __restrict__ Ftp, float* __restrict__ G,
    u16* __restrict__ Ht) {
  int bx = blockIdx.x;
  const u16 *A, *Bt;
  const float* bias;
  void* Y;
  int m0, epi, omode;
  if (bx < 16)       { A = output_bf;  Bt = Wdt;   bias = dec_b;   Y = E;   m0 = bx * 64;        epi = 1; omode = 0; }
  else if (bx < 80)  { A = context_bf; Bt = Wat;   bias = attn_b;  Y = Ftp; m0 = (bx - 16) * 64; epi = 1; omode = 1; }
  else if (bx < 96)  { A = output_bf;  Bt = Wot2t; bias = out_b;   Y = G;   m0 = (bx - 80) * 64; epi = 0; omode = 0; }
  else               { A = context_bf; Bt = Wot1t; bias = nullptr; Y = Ht;  m0 = (bx - 96) * 64; epi = 0; omode = 2; }
  gemm64_body(A, Bt, bias, Y, m0, blockIdx.y * 64, epi, omode);
}

// ---------------------------------------------------------------------------
// final: out = tanh(attn_bf @ Ht^T + G). 32x64 tile, K=512 (s), grid (32, 8).
// Both operands bf16 contiguous. G f32 added in epilogue.
// ---------------------------------------------------------------------------
__global__ __launch_bounds__(256) void final_gemm(
    const u16* __restrict__ attn_bf, const u16* __restrict__ Ht,
    const float* __restrict__ G, float* __restrict__ out) {
  int m0 = blockIdx.x * 32, n0 = blockIdx.y * 64;
  int b = m0 >> 7;   // T = 128
  const u16* Htb = Ht + (size_t)b * 512 * 512;

  __shared__ u16 As[32][40];
  __shared__ u16 Bs[64][40];
  int t = threadIdx.x;
  int lane = t & 63, wid = t >> 6, wm = wid >> 1, wn = wid & 1;
  int ar = t >> 2, ac = (t & 3) * 8;     // t<128 stages A (32 rows)
  int bn = t & 63, bk0 = (t >> 6) * 8;
  int fr = lane & 15, fh = (lane >> 4) * 8;

  const f32x4 fzero = {0.f, 0.f, 0.f, 0.f};
  f32x4 acc[2] = {fzero, fzero};

  short8 av, bv;
  auto loadA = [&](int k0) {
    if (t < 128)
      av = *(const short8*)(attn_bf + (size_t)(m0 + ar) * 512 + k0 + ac);
  };
  auto loadB = [&](int k0) {
    bv = *(const short8*)(Htb + (size_t)(n0 + bn) * 512 + k0 + bk0);
  };

  loadA(0); loadB(0);
  for (int k0 = 0; k0 < 512; k0 += 32) {
    if (k0) __syncthreads();
    if (t < 128) *(short8*)&As[ar][ac] = av;
    *(short8*)&Bs[bn][bk0] = bv;
    __syncthreads();
    short8 a0 = *(const short8*)&As[wm * 16 + fr][fh];
    short8 b0 = *(const short8*)&Bs[wn * 32 + fr][fh];
    short8 b1 = *(const short8*)&Bs[wn * 32 + 16 + fr][fh];
    if (k0 + 32 < 512) { loadA(k0 + 32); loadB(k0 + 32); }
    acc[0] = __builtin_amdgcn_mfma_f32_16x16x32_bf16(a0, b0, acc[0], 0, 0, 0);
    acc[1] = __builtin_amdgcn_mfma_f32_16x16x32_bf16(a0, b1, acc[1], 0, 0, 0);
  }

  int row0 = m0 + wm * 16 + ((lane >> 4) << 2);
#pragma unroll
  for (int qn = 0; qn < 2; ++qn) {
    int col = n0 + wn * 32 + qn * 16 + (lane & 15);
#pragma unroll
    for (int j = 0; j < 4; ++j) {
      float v = acc[qn][j] + G[(size_t)(row0 + j) * 512 + col];
      float e = __builtin_amdgcn_exp2f(v * TANH_SCALE);
      v = fmaf(-2.0f, __builtin_amdgcn_rcpf(e + 1.0f), 1.0f);
      out[(size_t)(row0 + j) * 512 + col] = v;
    }
  }
}

// ---------------------------------------------------------------------------
// Fused logits+softmax. logit[t,s] = base - 2*sum_d q_d/(E[t,d]*F[s,d]+1).
// grid = B*T/4 = 256 blocks (XCD-swizzled, 1/CU), block = 1024 (16 waves,
// 4 waves/SIMD). Block: 4 t-rows x 512 s -> F slab read once per 4 rows.
// Wave: 2 t-rows x 64 s (same inner loop as R9). E/q wave-uniform -> SGPR.
// Emits fp32 attn (output) + bf16 attn (for final_gemm).
// ---------------------------------------------------------------------------
__global__ __launch_bounds__(1024) void logits_softmax_kernel(
    const float* __restrict__ E, const float* __restrict__ Ftp,
    const float* __restrict__ qw, const float* __restrict__ qb,
    float* __restrict__ attn, u16* __restrict__ attn_bf) {
  int bid = blockIdx.x;
  int logical = ((bid & 7) << 5) | (bid >> 3);  // XCD x <- batch x (32 blocks)
  int bt0 = logical * 4;
  int b = logical >> 5;                          // = bt0 >> 7, T = 128
  int tid = threadIdx.x;
  int lane = tid & 63;
  int wv = __builtin_amdgcn_readfirstlane(tid >> 6);  // 0..15
  int th = wv >> 3;        // t-pair: rows {bt0+2th, bt0+2th+1}
  int sc = wv & 7;         // s-chunk
  int s = sc * 64 + lane;

  float qsum = 0.f;
#pragma unroll
  for (int i = 0; i < 8; ++i) qsum += qw[lane + 64 * i];
#pragma unroll
  for (int off = 32; off > 0; off >>= 1) qsum += __shfl_xor(qsum, off, 64);
  float base = qsum + qb[0];

  const float* Fp = Ftp + (size_t)b * 262144 + (size_t)s * 8;  // [g][s][8]
  const float* Et0 = E + (size_t)(bt0 + th * 2) * 512;
  const float* Et1 = Et0 + 512;

  float a0A = 0.f, a0B = 0.f, a1A = 0.f, a1B = 0.f;

  auto quad = [&](const f32x4& e, const f32x4& fc, const f32x4& q4, float& acc) {
    float x0 = fmaf(e[0], fc[0], 1.f), x1 = fmaf(e[1], fc[1], 1.f);
    float x2 = fmaf(e[2], fc[2], 1.f), x3 = fmaf(e[3], fc[3], 1.f);
    float dA = x0 * x1, dB = x2 * x3;
    float nA = fmaf(q4[0], x1, q4[1] * x0);
    float nB = fmaf(q4[2], x3, q4[3] * x2);
    float N = fmaf(nA, dB, nB * dA);
    acc = fmaf(N, __builtin_amdgcn_rcpf(dA * dB), acc);
  };

#pragma unroll 4
  for (int g = 0; g < 64; ++g) {
    f32x4 f0 = *(const f32x4*)(Fp + (size_t)g * 4096);
    f32x4 f1 = *(const f32x4*)(Fp + (size_t)g * 4096 + 4);
    f32x4 q0 = *(const f32x4*)(qw + g * 8);
    f32x4 q1 = *(const f32x4*)(qw + g * 8 + 4);
    f32x4 e00 = *(const f32x4*)(Et0 + g * 8);
    f32x4 e01 = *(const f32x4*)(Et0 + g * 8 + 4);
    f32x4 e10 = *(const f32x4*)(Et1 + g * 8);
    f32x4 e11 = *(const f32x4*)(Et1 + g * 8 + 4);
    quad(e00, f0, q0, a0A);
    quad(e01, f1, q1, a0B);
    quad(e10, f0, q0, a1A);
    quad(e11, f1, q1, a1B);
  }

  float l0 = fmaf(-2.f, a0A + a0B, base);
  float l1 = fmaf(-2.f, a1A + a1B, base);

  __shared__ float rmax[4][8], rsum[4][8];
  float m0 = l0, m1 = l1;
#pragma unroll
  for (int off = 32; off > 0; off >>= 1) {
    m0 = fmaxf(m0, __shfl_xor(m0, off, 64));
    m1 = fmaxf(m1, __shfl_xor(m1, off, 64));
  }
  int r0 = th * 2, r1 = th * 2 + 1;
  if (lane == 0) { rmax[r0][sc] = m0; rmax[r1][sc] = m1; }
  __syncthreads();
  float M0 = rmax[r0][0], M1 = rmax[r1][0];
#pragma unroll
  for (int i = 1; i < 8; ++i) {
    M0 = fmaxf(M0, rmax[r0][i]);
    M1 = fmaxf(M1, rmax[r1][i]);
  }
  float ex0 = __builtin_amdgcn_exp2f((l0 - M0) * LOG2E);
  float ex1 = __builtin_amdgcn_exp2f((l1 - M1) * LOG2E);
  float s0v = ex0, s1v = ex1;
#pragma unroll
  for (int off = 32; off > 0; off >>= 1) {
    s0v += __shfl_xor(s0v, off, 64);
    s1v += __shfl_xor(s1v, off, 64);
  }
  if (lane == 0) { rsum[r0][sc] = s0v; rsum[r1][sc] = s1v; }
  __syncthreads();
  float S0 = 0.f, S1 = 0.f;
#pragma unroll
  for (int i = 0; i < 8; ++i) { S0 += rsum[r0][i]; S1 += rsum[r1][i]; }
  float o0 = ex0 * __builtin_amdgcn_rcpf(S0);
  float o1 = ex1 * __builtin_amdgcn_rcpf(S1);
  size_t i0 = (size_t)(bt0 + r0) * 512 + s;
  size_t i1 = (size_t)(bt0 + r1) * 512 + s;
  attn[i0] = o0;
  attn[i1] = o1;
  attn_bf[i0] = f2bf(o0);
  attn_bf[i1] = f2bf(o1);
}

extern "C" void kernel_launch(void* const* d_in, const int* in_sizes, int n_in,
                              void* d_out, int out_size, void* d_ws, size_t ws_size,
                              hipStream_t stream) {
  const float* output  = (const float*)d_in[0];  // [B,T,D]
  const float* context = (const float*)d_in[1];  // [B,S,C]
  const float* dec_w   = (const float*)d_in[2];  // [D,D]
  const float* dec_b   = (const float*)d_in[3];
  const float* attn_w  = (const float*)d_in[4];  // [C,D]
  const float* attn_b  = (const float*)d_in[5];
  const float* qw      = (const float*)d_in[6];  // [D,1]
  const float* qb      = (const float*)d_in[7];  // [1]
  const float* out_w   = (const float*)d_in[8];  // [1024,512]
  const float* out_b   = (const float*)d_in[9];

  float* out_p  = (float*)d_out;                     // [B,T,D]
  float* attn_p = out_p + (size_t)BB * TT_DIM * DD;  // [B,T,S]

  char* p = (char*)d_ws;
  float* E    = (float*)p; p += (size_t)BB * TT_DIM * DD * 4;  // 2MB
  float* Ftp  = (float*)p; p += (size_t)BB * SS * DD * 4;      // 8MB packed^T
  float* G    = (float*)p; p += (size_t)BB * TT_DIM * DD * 4;  // 2MB
  u16* Ht     = (u16*)p;   p += (size_t)BB * SS * DD * 2;      // 4MB bf16 ^T
  u16* output_bf  = (u16*)p; p += (size_t)BB * TT_DIM * DD * 2;  // 1MB
  u16* context_bf = (u16*)p; p += (size_t)BB * SS * DD * 2;      // 4MB
  u16* attn_bf    = (u16*)p; p += (size_t)BB * TT_DIM * SS * 2;  // 1MB
  u16* Wdt   = (u16*)p; p += (size_t)DD * DD * 2;                // 512KB
  u16* Wat   = (u16*)p; p += (size_t)DD * DD * 2;                // 512KB
  u16* Wot1t = (u16*)p; p += (size_t)DD * DD * 2;                // 512KB
  u16* Wot2t = (u16*)p; p += (size_t)DD * DD * 2;                // 512KB

  prep_kernel<<<dim3(32 + 512), 256, 0, stream>>>(
      output, context, dec_w, attn_w, out_w,
      output_bf, context_bf, Wdt, Wat, Wot1t, Wot2t);
  ef_gemm<<<dim3(160, 8), 256, 0, stream>>>(
      output_bf, context_bf, Wdt, Wat, Wot1t, Wot2t,
      dec_b, attn_b, out_b, E, Ftp, G, Ht);
  logits_softmax_kernel<<<dim3(BB * TT_DIM / 4), 1024, 0, stream>>>(
      E, Ftp, qw, qb, attn_p, attn_bf);
  final_gemm<<<dim3(32, 8), 256, 0, stream>>>(attn_bf, Ht, G, out_p);
}

// Round 11
// 70.241 us; speedup vs baseline: 1.0722x; 1.0722x over previous
//
#include <hip/hip_runtime.h>

#define BB 8
#define TT_DIM 128
#define SS 512
#define DD 512
#define TANH_SCALE 2.885390081777927f   // 2*log2(e)
#define LOG2E 1.4426950408889634f

typedef unsigned short u16;
typedef short short8 __attribute__((ext_vector_type(8)));
typedef short short4v __attribute__((ext_vector_type(4)));
typedef float f32x4 __attribute__((ext_vector_type(4)));

__device__ __forceinline__ u16 f2bf(float f) {
  union { float f; unsigned u; } v; v.f = f;
  return (u16)((v.u + 0x7FFFu + ((v.u >> 16) & 1u)) >> 16);
}
__device__ __forceinline__ short8 cvt8(f32x4 a, f32x4 b) {
  short8 o;
  o[0] = (short)f2bf(a[0]); o[1] = (short)f2bf(a[1]);
  o[2] = (short)f2bf(a[2]); o[3] = (short)f2bf(a[3]);
  o[4] = (short)f2bf(b[0]); o[5] = (short)f2bf(b[1]);
  o[6] = (short)f2bf(b[2]); o[7] = (short)f2bf(b[3]);
  return o;
}

// ---------------------------------------------------------------------------
// 64x64 MFMA GEMM body (fp32 A/B in), K=512, strides 512.  (R9 proven)
// epi=1: exp(2x).  omode: 0 = plain fp32 Y[m,:]
//                          1 = packed transpose fp32  Y[b][d>>3][s][d&7] (Ftp)
//                          2 = transpose bf16         Y[b][col][srow]    (Ht)
// ---------------------------------------------------------------------------
__device__ __forceinline__ void gemm64_body(
    const float* __restrict__ A, const float* __restrict__ B,
    const float* __restrict__ bias, void* __restrict__ Y,
    int m0, int n0, int epi, int omode) {
  __shared__ u16 As[64][40];
  __shared__ u16 Bs[64][40];
  int t = threadIdx.x;
  int lane = t & 63, wid = t >> 6, wm = wid >> 1, wn = wid & 1;
  int ar = t >> 2, ac = (t & 3) * 8;
  int bn = t & 63, bk0 = (t >> 6) * 8;
  int fr = lane & 15, fh = (lane >> 4) * 8;

  const f32x4 fzero = {0.f, 0.f, 0.f, 0.f};
  f32x4 acc[2][2];
#pragma unroll
  for (int i = 0; i < 2; ++i)
#pragma unroll
    for (int j = 0; j < 2; ++j) acc[i][j] = fzero;

  short8 av, bv;
  auto loadA = [&](int k0) {
    const float* p = A + (size_t)(m0 + ar) * 512 + k0 + ac;
    av = cvt8(*(const f32x4*)p, *(const f32x4*)(p + 4));
  };
  auto loadB = [&](int k0) {
    const float* p = B + (size_t)(k0 + bk0) * 512 + n0 + bn;
#pragma unroll
    for (int i = 0; i < 8; ++i) bv[i] = (short)f2bf(p[(size_t)i * 512]);
  };

  loadA(0); loadB(0);
  for (int k0 = 0; k0 < 512; k0 += 32) {
    if (k0) __syncthreads();
    *(short8*)&As[ar][ac] = av;
    *(short8*)&Bs[bn][bk0] = bv;
    __syncthreads();
    short8 a0 = *(const short8*)&As[wm * 32 + fr][fh];
    short8 a1 = *(const short8*)&As[wm * 32 + 16 + fr][fh];
    short8 b0 = *(const short8*)&Bs[wn * 32 + fr][fh];
    short8 b1 = *(const short8*)&Bs[wn * 32 + 16 + fr][fh];
    if (k0 + 32 < 512) { loadA(k0 + 32); loadB(k0 + 32); }
    acc[0][0] = __builtin_amdgcn_mfma_f32_16x16x32_bf16(a0, b0, acc[0][0], 0, 0, 0);
    acc[0][1] = __builtin_amdgcn_mfma_f32_16x16x32_bf16(a0, b1, acc[0][1], 0, 0, 0);
    acc[1][0] = __builtin_amdgcn_mfma_f32_16x16x32_bf16(a1, b0, acc[1][0], 0, 0, 0);
    acc[1][1] = __builtin_amdgcn_mfma_f32_16x16x32_bf16(a1, b1, acc[1][1], 0, 0, 0);
  }

  // C/D layout (m89): col = lane&15, row = (lane>>4)*4 + j
#pragma unroll
  for (int qa = 0; qa < 2; ++qa) {
    int rbase = wm * 32 + qa * 16 + ((lane >> 4) << 2);
#pragma unroll
    for (int qn = 0; qn < 2; ++qn) {
      int col = n0 + wn * 32 + qn * 16 + (lane & 15);
      float bvs = bias ? bias[col] : 0.0f;
      f32x4 v4;
#pragma unroll
      for (int j = 0; j < 4; ++j) {
        float v = acc[qa][qn][j] + bvs;
        if (epi) v = __builtin_amdgcn_exp2f(v * TANH_SCALE);
        v4[j] = v;
      }
      int bb = m0 >> 9;
      int srow = (m0 & 511) + rbase;
      if (omode == 1) {          // packed transpose fp32 (Ftp[b][d>>3][s][d&7])
        float* Yf = (float*)Y;
        size_t base = ((size_t)bb * 64 + (col >> 3)) * 4096 + (size_t)(col & 7);
#pragma unroll
        for (int j = 0; j < 4; ++j)
          Yf[base + (size_t)(srow + j) * 8] = v4[j];
      } else if (omode == 2) {   // transpose bf16 (Ht[b][col][srow])
        u16* Yh = (u16*)Y;
        short4v o;
#pragma unroll
        for (int j = 0; j < 4; ++j) o[j] = (short)f2bf(v4[j]);
        *(short4v*)&Yh[((size_t)bb * 512 + col) * 512 + srow] = o;
      } else {                   // plain fp32
        float* Yf = (float*)Y;
#pragma unroll
        for (int j = 0; j < 4; ++j)
          Yf[(size_t)(m0 + rbase + j) * 512 + col] = v4[j];
      }
    }
  }
}

// blocks [0,16):    E  = exp(2*(output@dec_w+dec_b))          [1024,512]
// blocks [16,80):   Ftp= exp(2*(context@attn_w+attn_b)) packed^T
// blocks [80,96):   G  = output@out_w[512:] + out_b           [1024,512]
// blocks [96,160):  Ht = (context@out_w[:512])^T bf16         [8][512d][512s]
__global__ __launch_bounds__(256) void ef_gemm(
    const float* __restrict__ output, const float* __restrict__ dec_w,
    const float* __restrict__ dec_b, const float* __restrict__ context,
    const float* __restrict__ attn_w, const float* __restrict__ attn_b,
    const float* __restrict__ out_w, const float* __restrict__ out_b,
    float* __restrict__ E, float* __restrict__ Ftp, float* __restrict__ G,
    u16* __restrict__ Ht) {
  int bx = blockIdx.x;
  const float *A, *Bm, *bias;
  void* Y;
  int m0, epi, omode;
  if (bx < 16)       { A = output;  Bm = dec_w;  bias = dec_b;  Y = E;   m0 = bx * 64;        epi = 1; omode = 0; }
  else if (bx < 80)  { A = context; Bm = attn_w; bias = attn_b; Y = Ftp; m0 = (bx - 16) * 64; epi = 1; omode = 1; }
  else if (bx < 96)  { A = output;  Bm = out_w + 512 * 512; bias = out_b; Y = G; m0 = (bx - 80) * 64; epi = 0; omode = 0; }
  else               { A = context; Bm = out_w; bias = nullptr; Y = Ht;  m0 = (bx - 96) * 64; epi = 0; omode = 2; }
  gemm64_body(A, Bm, bias, Y, m0, blockIdx.y * 64, epi, omode);
}

// ---------------------------------------------------------------------------
// final: out = tanh(attn @ Ht^T + G).  32x64 tile, K=512 (s), grid (32, 8).
// (R9 proven) A = attn fp32 (cvt in staging). B = Ht bf16 contiguous.
// ---------------------------------------------------------------------------
__global__ __launch_bounds__(256) void final_gemm(
    const float* __restrict__ attn, const u16* __restrict__ Ht,
    const float* __restrict__ G, float* __restrict__ out) {
  int m0 = blockIdx.x * 32, n0 = blockIdx.y * 64;
  int b = m0 >> 7;   // T = 128
  const u16* Htb = Ht + (size_t)b * 512 * 512;

  __shared__ u16 As[32][40];
  __shared__ u16 Bs[64][40];
  int t = threadIdx.x;
  int lane = t & 63, wid = t >> 6, wm = wid >> 1, wn = wid & 1;
  int ar = t >> 2, ac = (t & 3) * 8;     // t<128 stages A (32 rows)
  int bn = t & 63, bk0 = (t >> 6) * 8;
  int fr = lane & 15, fh = (lane >> 4) * 8;

  const f32x4 fzero = {0.f, 0.f, 0.f, 0.f};
  f32x4 acc[2] = {fzero, fzero};

  short8 av, bv;
  auto loadA = [&](int k0) {
    if (t < 128) {
      const float* p = attn + (size_t)(m0 + ar) * 512 + k0 + ac;
      av = cvt8(*(const f32x4*)p, *(const f32x4*)(p + 4));
    }
  };
  auto loadB = [&](int k0) {
    bv = *(const short8*)(Htb + (size_t)(n0 + bn) * 512 + k0 + bk0);
  };

  loadA(0); loadB(0);
  for (int k0 = 0; k0 < 512; k0 += 32) {
    if (k0) __syncthreads();
    if (t < 128) *(short8*)&As[ar][ac] = av;
    *(short8*)&Bs[bn][bk0] = bv;
    __syncthreads();
    short8 a0 = *(const short8*)&As[wm * 16 + fr][fh];
    short8 b0 = *(const short8*)&Bs[wn * 32 + fr][fh];
    short8 b1 = *(const short8*)&Bs[wn * 32 + 16 + fr][fh];
    if (k0 + 32 < 512) { loadA(k0 + 32); loadB(k0 + 32); }
    acc[0] = __builtin_amdgcn_mfma_f32_16x16x32_bf16(a0, b0, acc[0], 0, 0, 0);
    acc[1] = __builtin_amdgcn_mfma_f32_16x16x32_bf16(a0, b1, acc[1], 0, 0, 0);
  }

  int row0 = m0 + wm * 16 + ((lane >> 4) << 2);
#pragma unroll
  for (int qn = 0; qn < 2; ++qn) {
    int col = n0 + wn * 32 + qn * 16 + (lane & 15);
#pragma unroll
    for (int j = 0; j < 4; ++j) {
      float v = acc[qn][j] + G[(size_t)(row0 + j) * 512 + col];
      float e = __builtin_amdgcn_exp2f(v * TANH_SCALE);
      v = fmaf(-2.0f, __builtin_amdgcn_rcpf(e + 1.0f), 1.0f);
      out[(size_t)(row0 + j) * 512 + col] = v;
    }
  }
}

// ---------------------------------------------------------------------------
// Fused logits+softmax. logit[t,s] = base - 2*sum_d q_d/(E[t,d]*F[s,d]+1).
// grid = B*T/4 = 256 blocks (XCD-swizzled, 1/CU), block = 1024 (16 waves,
// 4 waves/SIMD — same wave density as R9). Block: 4 t-rows x 512 s
// -> F-slab L2 traffic halved vs R9 (256 MB total).
// Wave: 2 t-rows x 64 s, lane = s; E/q wave-uniform -> SGPR loads.
// 4 d's share one rcp: sum q_i/x_i = (nA*dB + nB*dA)/(dA*dB).
// ---------------------------------------------------------------------------
__global__ __launch_bounds__(1024) void logits_softmax_kernel(
    const float* __restrict__ E, const float* __restrict__ Ftp,
    const float* __restrict__ qw, const float* __restrict__ qb,
    float* __restrict__ attn) {
  int bid = blockIdx.x;
  int logical = ((bid & 7) << 5) | (bid >> 3);  // 32 blocks/batch per XCD
  int bt0 = logical * 4;
  int b = logical >> 5;                          // = bt0 >> 7, T = 128
  int tid = threadIdx.x;
  int lane = tid & 63;
  int wv = __builtin_amdgcn_readfirstlane(tid >> 6);  // 0..15
  int th = wv >> 3;        // t-pair: rows {2th, 2th+1} of the 4
  int sc = wv & 7;         // s-chunk
  int s = sc * 64 + lane;

  float qsum = 0.f;
#pragma unroll
  for (int i = 0; i < 8; ++i) qsum += qw[lane + 64 * i];
#pragma unroll
  for (int off = 32; off > 0; off >>= 1) qsum += __shfl_xor(qsum, off, 64);
  float base = qsum + qb[0];

  const float* Fp = Ftp + (size_t)b * 262144 + (size_t)s * 8;  // [g][s][8]
  const float* Et0 = E + (size_t)(bt0 + th * 2) * 512;
  const float* Et1 = Et0 + 512;

  float a0A = 0.f, a0B = 0.f, a1A = 0.f, a1B = 0.f;

  auto quad = [&](const f32x4& e, const f32x4& fc, const f32x4& q4, float& acc) {
    float x0 = fmaf(e[0], fc[0], 1.f), x1 = fmaf(e[1], fc[1], 1.f);
    float x2 = fmaf(e[2], fc[2], 1.f), x3 = fmaf(e[3], fc[3], 1.f);
    float dA = x0 * x1, dB = x2 * x3;
    float nA = fmaf(q4[0], x1, q4[1] * x0);
    float nB = fmaf(q4[2], x3, q4[3] * x2);
    float N = fmaf(nA, dB, nB * dA);
    acc = fmaf(N, __builtin_amdgcn_rcpf(dA * dB), acc);
  };

#pragma unroll 4
  for (int g = 0; g < 64; ++g) {
    f32x4 f0 = *(const f32x4*)(Fp + (size_t)g * 4096);
    f32x4 f1 = *(const f32x4*)(Fp + (size_t)g * 4096 + 4);
    f32x4 q0 = *(const f32x4*)(qw + g * 8);
    f32x4 q1 = *(const f32x4*)(qw + g * 8 + 4);
    f32x4 e00 = *(const f32x4*)(Et0 + g * 8);
    f32x4 e01 = *(const f32x4*)(Et0 + g * 8 + 4);
    f32x4 e10 = *(const f32x4*)(Et1 + g * 8);
    f32x4 e11 = *(const f32x4*)(Et1 + g * 8 + 4);
    quad(e00, f0, q0, a0A);
    quad(e01, f1, q1, a0B);
    quad(e10, f0, q0, a1A);
    quad(e11, f1, q1, a1B);
  }

  float l0 = fmaf(-2.f, a0A + a0B, base);
  float l1 = fmaf(-2.f, a1A + a1B, base);

  __shared__ float rmax[4][8], rsum[4][8];
  float m0 = l0, m1 = l1;
#pragma unroll
  for (int off = 32; off > 0; off >>= 1) {
    m0 = fmaxf(m0, __shfl_xor(m0, off, 64));
    m1 = fmaxf(m1, __shfl_xor(m1, off, 64));
  }
  int r0 = th * 2, r1 = th * 2 + 1;
  if (lane == 0) { rmax[r0][sc] = m0; rmax[r1][sc] = m1; }
  __syncthreads();
  float M0 = rmax[r0][0], M1 = rmax[r1][0];
#pragma unroll
  for (int i = 1; i < 8; ++i) {
    M0 = fmaxf(M0, rmax[r0][i]);
    M1 = fmaxf(M1, rmax[r1][i]);
  }
  float ex0 = __builtin_amdgcn_exp2f((l0 - M0) * LOG2E);
  float ex1 = __builtin_amdgcn_exp2f((l1 - M1) * LOG2E);
  float s0v = ex0, s1v = ex1;
#pragma unroll
  for (int off = 32; off > 0; off >>= 1) {
    s0v += __shfl_xor(s0v, off, 64);
    s1v += __shfl_xor(s1v, off, 64);
  }
  if (lane == 0) { rsum[r0][sc] = s0v; rsum[r1][sc] = s1v; }
  __syncthreads();
  float S0 = 0.f, S1 = 0.f;
#pragma unroll
  for (int i = 0; i < 8; ++i) { S0 += rsum[r0][i]; S1 += rsum[r1][i]; }
  attn[(size_t)(bt0 + r0) * 512 + s] = ex0 * __builtin_amdgcn_rcpf(S0);
  attn[(size_t)(bt0 + r1) * 512 + s] = ex1 * __builtin_amdgcn_rcpf(S1);
}

extern "C" void kernel_launch(void* const* d_in, const int* in_sizes, int n_in,
                              void* d_out, int out_size, void* d_ws, size_t ws_size,
                              hipStream_t stream) {
  const float* output  = (const float*)d_in[0];  // [B,T,D]
  const float* context = (const float*)d_in[1];  // [B,S,C]
  const float* dec_w   = (const float*)d_in[2];  // [D,D]
  const float* dec_b   = (const float*)d_in[3];
  const float* attn_w  = (const float*)d_in[4];  // [C,D]
  const float* attn_b  = (const float*)d_in[5];
  const float* qw      = (const float*)d_in[6];  // [D,1]
  const float* qb      = (const float*)d_in[7];  // [1]
  const float* out_w   = (const float*)d_in[8];  // [1024,512]
  const float* out_b   = (const float*)d_in[9];

  float* out_p  = (float*)d_out;                     // [B,T,D]
  float* attn_p = out_p + (size_t)BB * TT_DIM * DD;  // [B,T,S]

  char* p = (char*)d_ws;
  float* E   = (float*)p; p += (size_t)BB * TT_DIM * DD * 4;  // 2MB
  float* Ftp = (float*)p; p += (size_t)BB * SS * DD * 4;      // 8MB packed^T
  float* G   = (float*)p; p += (size_t)BB * TT_DIM * DD * 4;  // 2MB
  u16* Ht    = (u16*)p;   p += (size_t)BB * SS * DD * 2;      // 4MB bf16 ^T

  ef_gemm<<<dim3(160, 8), 256, 0, stream>>>(output, dec_w, dec_b, context,
                                            attn_w, attn_b, out_w, out_b,
                                            E, Ftp, G, Ht);
  logits_softmax_kernel<<<dim3(BB * TT_DIM / 4), 1024, 0, stream>>>(
      E, Ftp, qw, qb, attn_p);
  final_gemm<<<dim3(32, 8), 256, 0, stream>>>(attn_p, Ht, G, out_p);
}

// Round 13
// 65.206 us; speedup vs baseline: 1.1550x; 1.0772x over previous
//
#include <hip/hip_runtime.h>
#include <hip/hip_bf16.h>

#define BB 8
#define TT_DIM 128
#define SS 512
#define DD 512
#define TANH_SCALE 2.885390081777927f   // 2*log2(e)
#define LOG2E 1.4426950408889634f

typedef unsigned short u16;
typedef unsigned int u32;
typedef short short8 __attribute__((ext_vector_type(8)));
typedef short short4v __attribute__((ext_vector_type(4)));
typedef float f32x4 __attribute__((ext_vector_type(4)));
typedef unsigned int u32x4 __attribute__((ext_vector_type(4)));

__device__ __forceinline__ u16 f2bf(float f) {
  __hip_bfloat16 h = __float2bfloat16(f);          // compiler emits v_cvt_pk
  return __builtin_bit_cast(u16, h);
}
__device__ __forceinline__ float bfhi2f(u32 w) {   // upper bf16 of dword
  return __builtin_bit_cast(float, w & 0xFFFF0000u);
}
__device__ __forceinline__ float bflo2f(u32 w) {   // lower bf16 of dword
  return __builtin_bit_cast(float, w << 16);
}
__device__ __forceinline__ short8 cvt8(f32x4 a, f32x4 b) {
  short8 o;
  o[0] = (short)f2bf(a[0]); o[1] = (short)f2bf(a[1]);
  o[2] = (short)f2bf(a[2]); o[3] = (short)f2bf(a[3]);
  o[4] = (short)f2bf(b[0]); o[5] = (short)f2bf(b[1]);
  o[6] = (short)f2bf(b[2]); o[7] = (short)f2bf(b[3]);
  return o;
}

// ---------------------------------------------------------------------------
// 64x64 MFMA GEMM body (fp32 A/B in), K=512, strides 512.
// epi=1: exp(2x).  omode: 0 = plain fp32 Y[m,:]
//                          1 = packed transpose BF16  Y[b][d>>3][s][d&7] (Ftp)
//                          2 = transpose bf16         Y[b][col][srow]    (Ht)
// ---------------------------------------------------------------------------
__device__ __forceinline__ void gemm64_body(
    const float* __restrict__ A, const float* __restrict__ B,
    const float* __restrict__ bias, void* __restrict__ Y,
    int m0, int n0, int epi, int omode) {
  __shared__ u16 As[64][40];
  __shared__ u16 Bs[64][40];
  int t = threadIdx.x;
  int lane = t & 63, wid = t >> 6, wm = wid >> 1, wn = wid & 1;
  int ar = t >> 2, ac = (t & 3) * 8;
  int bn = t & 63, bk0 = (t >> 6) * 8;
  int fr = lane & 15, fh = (lane >> 4) * 8;

  const f32x4 fzero = {0.f, 0.f, 0.f, 0.f};
  f32x4 acc[2][2];
#pragma unroll
  for (int i = 0; i < 2; ++i)
#pragma unroll
    for (int j = 0; j < 2; ++j) acc[i][j] = fzero;

  short8 av, bv;
  auto loadA = [&](int k0) {
    const float* p = A + (size_t)(m0 + ar) * 512 + k0 + ac;
    av = cvt8(*(const f32x4*)p, *(const f32x4*)(p + 4));
  };
  auto loadB = [&](int k0) {
    const float* p = B + (size_t)(k0 + bk0) * 512 + n0 + bn;
#pragma unroll
    for (int i = 0; i < 8; ++i) bv[i] = (short)f2bf(p[(size_t)i * 512]);
  };

  loadA(0); loadB(0);
  for (int k0 = 0; k0 < 512; k0 += 32) {
    if (k0) __syncthreads();
    *(short8*)&As[ar][ac] = av;
    *(short8*)&Bs[bn][bk0] = bv;
    __syncthreads();
    short8 a0 = *(const short8*)&As[wm * 32 + fr][fh];
    short8 a1 = *(const short8*)&As[wm * 32 + 16 + fr][fh];
    short8 b0 = *(const short8*)&Bs[wn * 32 + fr][fh];
    short8 b1 = *(const short8*)&Bs[wn * 32 + 16 + fr][fh];
    if (k0 + 32 < 512) { loadA(k0 + 32); loadB(k0 + 32); }
    acc[0][0] = __builtin_amdgcn_mfma_f32_16x16x32_bf16(a0, b0, acc[0][0], 0, 0, 0);
    acc[0][1] = __builtin_amdgcn_mfma_f32_16x16x32_bf16(a0, b1, acc[0][1], 0, 0, 0);
    acc[1][0] = __builtin_amdgcn_mfma_f32_16x16x32_bf16(a1, b0, acc[1][0], 0, 0, 0);
    acc[1][1] = __builtin_amdgcn_mfma_f32_16x16x32_bf16(a1, b1, acc[1][1], 0, 0, 0);
  }

  // C/D layout (m89): col = lane&15, row = (lane>>4)*4 + j
#pragma unroll
  for (int qa = 0; qa < 2; ++qa) {
    int rbase = wm * 32 + qa * 16 + ((lane >> 4) << 2);
#pragma unroll
    for (int qn = 0; qn < 2; ++qn) {
      int col = n0 + wn * 32 + qn * 16 + (lane & 15);
      float bvs = bias ? bias[col] : 0.0f;
      f32x4 v4;
#pragma unroll
      for (int j = 0; j < 4; ++j) {
        float v = acc[qa][qn][j] + bvs;
        if (epi) v = __builtin_amdgcn_exp2f(v * TANH_SCALE);
        v4[j] = v;
      }
      int bb = m0 >> 9;
      int srow = (m0 & 511) + rbase;
      if (omode == 1) {          // packed transpose BF16 (Ftp[b][d>>3][s][d&7])
        u16* Yh = (u16*)Y;
        size_t base = ((size_t)bb * 64 + (col >> 3)) * 4096 + (size_t)(col & 7);
#pragma unroll
        for (int j = 0; j < 4; ++j)
          Yh[base + (size_t)(srow + j) * 8] = f2bf(v4[j]);
      } else if (omode == 2) {   // transpose bf16 (Ht[b][col][srow])
        u16* Yh = (u16*)Y;
        short4v o;
#pragma unroll
        for (int j = 0; j < 4; ++j) o[j] = (short)f2bf(v4[j]);
        *(short4v*)&Yh[((size_t)bb * 512 + col) * 512 + srow] = o;
      } else {                   // plain fp32
        float* Yf = (float*)Y;
#pragma unroll
        for (int j = 0; j < 4; ++j)
          Yf[(size_t)(m0 + rbase + j) * 512 + col] = v4[j];
      }
    }
  }
}

// blocks [0,16):    E  = exp(2*(output@dec_w+dec_b))          [1024,512]
// blocks [16,80):   Ftp= exp(2*(context@attn_w+attn_b)) packed^T bf16
// blocks [80,96):   G  = output@out_w[512:] + out_b           [1024,512]
// blocks [96,160):  Ht = (context@out_w[:512])^T bf16         [8][512d][512s]
__global__ __launch_bounds__(256) void ef_gemm(
    const float* __restrict__ output, const float* __restrict__ dec_w,
    const float* __restrict__ dec_b, const float* __restrict__ context,
    const float* __restrict__ attn_w, const float* __restrict__ attn_b,
    const float* __restrict__ out_w, const float* __restrict__ out_b,
    float* __restrict__ E, u16* __restrict__ Ftp, float* __restrict__ G,
    u16* __restrict__ Ht) {
  int bx = blockIdx.x;
  const float *A, *Bm, *bias;
  void* Y;
  int m0, epi, omode;
  if (bx < 16)       { A = output;  Bm = dec_w;  bias = dec_b;  Y = E;   m0 = bx * 64;        epi = 1; omode = 0; }
  else if (bx < 80)  { A = context; Bm = attn_w; bias = attn_b; Y = Ftp; m0 = (bx - 16) * 64; epi = 1; omode = 1; }
  else if (bx < 96)  { A = output;  Bm = out_w + 512 * 512; bias = out_b; Y = G; m0 = (bx - 80) * 64; epi = 0; omode = 0; }
  else               { A = context; Bm = out_w; bias = nullptr; Y = Ht;  m0 = (bx - 96) * 64; epi = 0; omode = 2; }
  gemm64_body(A, Bm, bias, Y, m0, blockIdx.y * 64, epi, omode);
}

// ---------------------------------------------------------------------------
// final: out = tanh(attn @ Ht^T + G).  32x64 tile, K=512 (s), grid (32, 8).
// ---------------------------------------------------------------------------
__global__ __launch_bounds__(256) void final_gemm(
    const float* __restrict__ attn, const u16* __restrict__ Ht,
    const float* __restrict__ G, float* __restrict__ out) {
  int m0 = blockIdx.x * 32, n0 = blockIdx.y * 64;
  int b = m0 >> 7;   // T = 128
  const u16* Htb = Ht + (size_t)b * 512 * 512;

  __shared__ u16 As[32][40];
  __shared__ u16 Bs[64][40];
  int t = threadIdx.x;
  int lane = t & 63, wid = t >> 6, wm = wid >> 1, wn = wid & 1;
  int ar = t >> 2, ac = (t & 3) * 8;     // t<128 stages A (32 rows)
  int bn = t & 63, bk0 = (t >> 6) * 8;
  int fr = lane & 15, fh = (lane >> 4) * 8;

  const f32x4 fzero = {0.f, 0.f, 0.f, 0.f};
  f32x4 acc[2] = {fzero, fzero};

  short8 av, bv;
  auto loadA = [&](int k0) {
    if (t < 128) {
      const float* p = attn + (size_t)(m0 + ar) * 512 + k0 + ac;
      av = cvt8(*(const f32x4*)p, *(const f32x4*)(p + 4));
    }
  };
  auto loadB = [&](int k0) {
    bv = *(const short8*)(Htb + (size_t)(n0 + bn) * 512 + k0 + bk0);
  };

  loadA(0); loadB(0);
  for (int k0 = 0; k0 < 512; k0 += 32) {
    if (k0) __syncthreads();
    if (t < 128) *(short8*)&As[ar][ac] = av;
    *(short8*)&Bs[bn][bk0] = bv;
    __syncthreads();
    short8 a0 = *(const short8*)&As[wm * 16 + fr][fh];
    short8 b0 = *(const short8*)&Bs[wn * 32 + fr][fh];
    short8 b1 = *(const short8*)&Bs[wn * 32 + 16 + fr][fh];
    if (k0 + 32 < 512) { loadA(k0 + 32); loadB(k0 + 32); }
    acc[0] = __builtin_amdgcn_mfma_f32_16x16x32_bf16(a0, b0, acc[0], 0, 0, 0);
    acc[1] = __builtin_amdgcn_mfma_f32_16x16x32_bf16(a0, b1, acc[1], 0, 0, 0);
  }

  int row0 = m0 + wm * 16 + ((lane >> 4) << 2);
#pragma unroll
  for (int qn = 0; qn < 2; ++qn) {
    int col = n0 + wn * 32 + qn * 16 + (lane & 15);
#pragma unroll
    for (int j = 0; j < 4; ++j) {
      float v = acc[qn][j] + G[(size_t)(row0 + j) * 512 + col];
      float e = __builtin_amdgcn_exp2f(v * TANH_SCALE);
      v = fmaf(-2.0f, __builtin_amdgcn_rcpf(e + 1.0f), 1.0f);
      out[(size_t)(row0 + j) * 512 + col] = v;
    }
  }
}

// ---------------------------------------------------------------------------
// Fused logits+softmax. logit[t,s] = base - 2*sum_d q_d/(E[t,d]*F[s,d]+1).
// grid = B*T/4 = 256 blocks (XCD-swizzled), block = 1024 (16 waves).
// Block: 4 t-rows x 512 s. Wave: 2 t-rows x 64 s, lane = s.
// Ftp is BF16-packed [b][g][s][8]: ONE dwordx4 per lane per 8 d's.
// Per-g stride = 512 s * 8 bf16 = 8192 B = 512 u32x4 (R12 BUG was 256).
// E/q wave-uniform -> SGPR. 4 d's share one rcp.
// ---------------------------------------------------------------------------
__global__ __launch_bounds__(1024) void logits_softmax_kernel(
    const float* __restrict__ E, const u16* __restrict__ Ftp,
    const float* __restrict__ qw, const float* __restrict__ qb,
    float* __restrict__ attn) {
  int bid = blockIdx.x;
  int logical = ((bid & 7) << 5) | (bid >> 3);  // 32 blocks/batch per XCD
  int bt0 = logical * 4;
  int b = logical >> 5;                          // = bt0 >> 7, T = 128
  int tid = threadIdx.x;
  int lane = tid & 63;
  int wv = __builtin_amdgcn_readfirstlane(tid >> 6);  // 0..15
  int th = wv >> 3;        // t-pair: rows {2th, 2th+1} of the 4
  int sc = wv & 7;         // s-chunk
  int s = sc * 64 + lane;

  float qsum = 0.f;
#pragma unroll
  for (int i = 0; i < 8; ++i) qsum += qw[lane + 64 * i];
#pragma unroll
  for (int off = 32; off > 0; off >>= 1) qsum += __shfl_xor(qsum, off, 64);
  float base = qsum + qb[0];

  // Ftp[b][g][s][8] bf16; one uint4 = 8 bf16 per (g,s).
  const u32x4* Fp = (const u32x4*)(Ftp + (size_t)b * 262144 + (size_t)s * 8);
  const float* Et0 = E + (size_t)(bt0 + th * 2) * 512;
  const float* Et1 = Et0 + 512;

  float a0A = 0.f, a0B = 0.f, a1A = 0.f, a1B = 0.f;

  auto quad = [&](const f32x4& e, const f32x4& fc, const f32x4& q4, float& acc) {
    float x0 = fmaf(e[0], fc[0], 1.f), x1 = fmaf(e[1], fc[1], 1.f);
    float x2 = fmaf(e[2], fc[2], 1.f), x3 = fmaf(e[3], fc[3], 1.f);
    float dA = x0 * x1, dB = x2 * x3;
    float nA = fmaf(q4[0], x1, q4[1] * x0);
    float nB = fmaf(q4[2], x3, q4[3] * x2);
    float N = fmaf(nA, dB, nB * dA);
    acc = fmaf(N, __builtin_amdgcn_rcpf(dA * dB), acc);
  };

#pragma unroll 4
  for (int g = 0; g < 64; ++g) {
    u32x4 w = Fp[(size_t)g * 512];   // per-g stride = 8192 B = 512 u32x4
    f32x4 f0, f1;
    f0[0] = bflo2f(w[0]); f0[1] = bfhi2f(w[0]);
    f0[2] = bflo2f(w[1]); f0[3] = bfhi2f(w[1]);
    f1[0] = bflo2f(w[2]); f1[1] = bfhi2f(w[2]);
    f1[2] = bflo2f(w[3]); f1[3] = bfhi2f(w[3]);
    f32x4 q0 = *(const f32x4*)(qw + g * 8);
    f32x4 q1 = *(const f32x4*)(qw + g * 8 + 4);
    f32x4 e00 = *(const f32x4*)(Et0 + g * 8);
    f32x4 e01 = *(const f32x4*)(Et0 + g * 8 + 4);
    f32x4 e10 = *(const f32x4*)(Et1 + g * 8);
    f32x4 e11 = *(const f32x4*)(Et1 + g * 8 + 4);
    quad(e00, f0, q0, a0A);
    quad(e01, f1, q1, a0B);
    quad(e10, f0, q0, a1A);
    quad(e11, f1, q1, a1B);
  }

  float l0 = fmaf(-2.f, a0A + a0B, base);
  float l1 = fmaf(-2.f, a1A + a1B, base);

  __shared__ float rmax[4][8], rsum[4][8];
  float m0 = l0, m1 = l1;
#pragma unroll
  for (int off = 32; off > 0; off >>= 1) {
    m0 = fmaxf(m0, __shfl_xor(m0, off, 64));
    m1 = fmaxf(m1, __shfl_xor(m1, off, 64));
  }
  int r0 = th * 2, r1 = th * 2 + 1;
  if (lane == 0) { rmax[r0][sc] = m0; rmax[r1][sc] = m1; }
  __syncthreads();
  float M0 = rmax[r0][0], M1 = rmax[r1][0];
#pragma unroll
  for (int i = 1; i < 8; ++i) {
    M0 = fmaxf(M0, rmax[r0][i]);
    M1 = fmaxf(M1, rmax[r1][i]);
  }
  float ex0 = __builtin_amdgcn_exp2f((l0 - M0) * LOG2E);
  float ex1 = __builtin_amdgcn_exp2f((l1 - M1) * LOG2E);
  float s0v = ex0, s1v = ex1;
#pragma unroll
  for (int off = 32; off > 0; off >>= 1) {
    s0v += __shfl_xor(s0v, off, 64);
    s1v += __shfl_xor(s1v, off, 64);
  }
  if (lane == 0) { rsum[r0][sc] = s0v; rsum[r1][sc] = s1v; }
  __syncthreads();
  float S0 = 0.f, S1 = 0.f;
#pragma unroll
  for (int i = 0; i < 8; ++i) { S0 += rsum[r0][i]; S1 += rsum[r1][i]; }
  attn[(size_t)(bt0 + r0) * 512 + s] = ex0 * __builtin_amdgcn_rcpf(S0);
  attn[(size_t)(bt0 + r1) * 512 + s] = ex1 * __builtin_amdgcn_rcpf(S1);
}

extern "C" void kernel_launch(void* const* d_in, const int* in_sizes, int n_in,
                              void* d_out, int out_size, void* d_ws, size_t ws_size,
                              hipStream_t stream) {
  const float* output  = (const float*)d_in[0];  // [B,T,D]
  const float* context = (const float*)d_in[1];  // [B,S,C]
  const float* dec_w   = (const float*)d_in[2];  // [D,D]
  const float* dec_b   = (const float*)d_in[3];
  const float* attn_w  = (const float*)d_in[4];  // [C,D]
  const float* attn_b  = (const float*)d_in[5];
  const float* qw      = (const float*)d_in[6];  // [D,1]
  const float* qb      = (const float*)d_in[7];  // [1]
  const float* out_w   = (const float*)d_in[8];  // [1024,512]
  const float* out_b   = (const float*)d_in[9];

  float* out_p  = (float*)d_out;                     // [B,T,D]
  float* attn_p = out_p + (size_t)BB * TT_DIM * DD;  // [B,T,S]

  char* p = (char*)d_ws;
  float* E   = (float*)p; p += (size_t)BB * TT_DIM * DD * 4;  // 2MB
  u16* Ftp   = (u16*)p;   p += (size_t)BB * SS * DD * 2;      // 4MB packed^T bf16
  float* G   = (float*)p; p += (size_t)BB * TT_DIM * DD * 4;  // 2MB
  u16* Ht    = (u16*)p;   p += (size_t)BB * SS * DD * 2;      // 4MB bf16 ^T

  ef_gemm<<<dim3(160, 8), 256, 0, stream>>>(output, dec_w, dec_b, context,
                                            attn_w, attn_b, out_w, out_b,
                                            E, Ftp, G, Ht);
  logits_softmax_kernel<<<dim3(BB * TT_DIM / 4), 1024, 0, stream>>>(
      E, Ftp, qw, qb, attn_p);
  final_gemm<<<dim3(32, 8), 256, 0, stream>>>(attn_p, Ht, G, out_p);
}

// Round 14
// 63.617 us; speedup vs baseline: 1.1839x; 1.0250x over previous
//
#include <hip/hip_runtime.h>
#include <hip/hip_bf16.h>

#define BB 8
#define TT_DIM 128
#define SS 512
#define DD 512
#define TANH_SCALE 2.885390081777927f   // 2*log2(e)
#define LOG2E 1.4426950408889634f

typedef unsigned short u16;
typedef unsigned int u32;
typedef short short8 __attribute__((ext_vector_type(8)));
typedef short short4v __attribute__((ext_vector_type(4)));
typedef float f32x4 __attribute__((ext_vector_type(4)));
typedef unsigned int u32x4 __attribute__((ext_vector_type(4)));

__device__ __forceinline__ u16 f2bf(float f) {
  __hip_bfloat16 h = __float2bfloat16(f);
  return __builtin_bit_cast(u16, h);
}
__device__ __forceinline__ float bfhi2f(u32 w) {
  return __builtin_bit_cast(float, w & 0xFFFF0000u);
}
__device__ __forceinline__ float bflo2f(u32 w) {
  return __builtin_bit_cast(float, w << 16);
}
__device__ __forceinline__ short8 cvt8(f32x4 a, f32x4 b) {
  short8 o;
  o[0] = (short)f2bf(a[0]); o[1] = (short)f2bf(a[1]);
  o[2] = (short)f2bf(a[2]); o[3] = (short)f2bf(a[3]);
  o[4] = (short)f2bf(b[0]); o[5] = (short)f2bf(b[1]);
  o[6] = (short)f2bf(b[2]); o[7] = (short)f2bf(b[3]);
  return o;
}

// ---------------------------------------------------------------------------
// Fused dual-GEMM: one A tile, TWO B matrices (A re-read halved vs separate).
// bx<16:   A=output [1024,512]: Y1=E=exp(2*(A@dec_w+dec_b)), Y2=G=A@out_w2+out_b
// bx>=16:  A=context[4096,512]: Y1=Ftp=exp(2*(A@attn_w+attn_b)) packed^T bf16,
//                               Y2=Ht=(A@out_w1)^T bf16
// 64x64 tile, 4 waves (2x2), wave=32x32 via 2x2 mfma. 8 MFMA/k-step.
// ---------------------------------------------------------------------------
__global__ __launch_bounds__(256) void ef_gemm(
    const float* __restrict__ output, const float* __restrict__ context,
    const float* __restrict__ dec_w, const float* __restrict__ attn_w,
    const float* __restrict__ out_w,
    const float* __restrict__ dec_b, const float* __restrict__ attn_b,
    const float* __restrict__ out_b,
    float* __restrict__ E, u16* __restrict__ Ftp,
    float* __restrict__ G, u16* __restrict__ Ht) {
  int bx = blockIdx.x;
  bool isF = bx >= 16;
  const float* A  = isF ? context : output;
  const float* B1 = isF ? attn_w : dec_w;
  const float* B2 = isF ? out_w : out_w + 512 * 512;
  const float* bias1 = isF ? attn_b : dec_b;
  int m0 = (isF ? bx - 16 : bx) * 64;
  int n0 = blockIdx.y * 64;

  __shared__ u16 As[64][40];
  __shared__ u16 Bs1[64][40];
  __shared__ u16 Bs2[64][40];
  int t = threadIdx.x;
  int lane = t & 63, wid = t >> 6, wm = wid >> 1, wn = wid & 1;
  int ar = t >> 2, ac = (t & 3) * 8;
  int bn = t & 63, bk0 = (t >> 6) * 8;
  int fr = lane & 15, fh = (lane >> 4) * 8;

  const f32x4 fzero = {0.f, 0.f, 0.f, 0.f};
  f32x4 acc1[2][2], acc2[2][2];
#pragma unroll
  for (int i = 0; i < 2; ++i)
#pragma unroll
    for (int j = 0; j < 2; ++j) { acc1[i][j] = fzero; acc2[i][j] = fzero; }

  short8 av, bv1, bv2;
  auto loadA = [&](int k0) {
    const float* p = A + (size_t)(m0 + ar) * 512 + k0 + ac;
    av = cvt8(*(const f32x4*)p, *(const f32x4*)(p + 4));
  };
  auto loadB = [&](const float* B, int k0, short8& dst) {
    const float* p = B + (size_t)(k0 + bk0) * 512 + n0 + bn;
#pragma unroll
    for (int i = 0; i < 8; ++i) dst[i] = (short)f2bf(p[(size_t)i * 512]);
  };

  loadA(0); loadB(B1, 0, bv1); loadB(B2, 0, bv2);
  for (int k0 = 0; k0 < 512; k0 += 32) {
    if (k0) __syncthreads();
    *(short8*)&As[ar][ac] = av;
    *(short8*)&Bs1[bn][bk0] = bv1;
    *(short8*)&Bs2[bn][bk0] = bv2;
    __syncthreads();
    short8 a0 = *(const short8*)&As[wm * 32 + fr][fh];
    short8 a1 = *(const short8*)&As[wm * 32 + 16 + fr][fh];
    short8 p0 = *(const short8*)&Bs1[wn * 32 + fr][fh];
    short8 p1 = *(const short8*)&Bs1[wn * 32 + 16 + fr][fh];
    short8 r0 = *(const short8*)&Bs2[wn * 32 + fr][fh];
    short8 r1 = *(const short8*)&Bs2[wn * 32 + 16 + fr][fh];
    if (k0 + 32 < 512) { loadA(k0 + 32); loadB(B1, k0 + 32, bv1); loadB(B2, k0 + 32, bv2); }
    acc1[0][0] = __builtin_amdgcn_mfma_f32_16x16x32_bf16(a0, p0, acc1[0][0], 0, 0, 0);
    acc1[0][1] = __builtin_amdgcn_mfma_f32_16x16x32_bf16(a0, p1, acc1[0][1], 0, 0, 0);
    acc1[1][0] = __builtin_amdgcn_mfma_f32_16x16x32_bf16(a1, p0, acc1[1][0], 0, 0, 0);
    acc1[1][1] = __builtin_amdgcn_mfma_f32_16x16x32_bf16(a1, p1, acc1[1][1], 0, 0, 0);
    acc2[0][0] = __builtin_amdgcn_mfma_f32_16x16x32_bf16(a0, r0, acc2[0][0], 0, 0, 0);
    acc2[0][1] = __builtin_amdgcn_mfma_f32_16x16x32_bf16(a0, r1, acc2[0][1], 0, 0, 0);
    acc2[1][0] = __builtin_amdgcn_mfma_f32_16x16x32_bf16(a1, r0, acc2[1][0], 0, 0, 0);
    acc2[1][1] = __builtin_amdgcn_mfma_f32_16x16x32_bf16(a1, r1, acc2[1][1], 0, 0, 0);
  }

  // C/D layout (m89): col = lane&15, row = (lane>>4)*4 + j
#pragma unroll
  for (int qa = 0; qa < 2; ++qa) {
    int rbase = wm * 32 + qa * 16 + ((lane >> 4) << 2);
#pragma unroll
    for (int qn = 0; qn < 2; ++qn) {
      int col = n0 + wn * 32 + qn * 16 + (lane & 15);
      float b1v = bias1[col];
      int bb = m0 >> 9;
      int srow = (m0 & 511) + rbase;
      if (isF) {
        size_t fbase = ((size_t)bb * 64 + (col >> 3)) * 4096 + (size_t)(col & 7);
        short4v ho;
#pragma unroll
        for (int j = 0; j < 4; ++j) {
          float v1 = __builtin_amdgcn_exp2f((acc1[qa][qn][j] + b1v) * TANH_SCALE);
          Ftp[fbase + (size_t)(srow + j) * 8] = f2bf(v1);
          ho[j] = (short)f2bf(acc2[qa][qn][j]);          // Ht: no bias
        }
        *(short4v*)&Ht[((size_t)bb * 512 + col) * 512 + srow] = ho;
      } else {
        float b2v = out_b[col];
#pragma unroll
        for (int j = 0; j < 4; ++j) {
          float v1 = __builtin_amdgcn_exp2f((acc1[qa][qn][j] + b1v) * TANH_SCALE);
          E[(size_t)(m0 + rbase + j) * 512 + col] = v1;
          G[(size_t)(m0 + rbase + j) * 512 + col] = acc2[qa][qn][j] + b2v;
        }
      }
    }
  }
}

// ---------------------------------------------------------------------------
// final: out = tanh(attn @ Ht^T + G).  32x64 tile, K=512 (s), grid (32, 8).
// ---------------------------------------------------------------------------
__global__ __launch_bounds__(256) void final_gemm(
    const float* __restrict__ attn, const u16* __restrict__ Ht,
    const float* __restrict__ G, float* __restrict__ out) {
  int m0 = blockIdx.x * 32, n0 = blockIdx.y * 64;
  int b = m0 >> 7;   // T = 128
  const u16* Htb = Ht + (size_t)b * 512 * 512;

  __shared__ u16 As[32][40];
  __shared__ u16 Bs[64][40];
  int t = threadIdx.x;
  int lane = t & 63, wid = t >> 6, wm = wid >> 1, wn = wid & 1;
  int ar = t >> 2, ac = (t & 3) * 8;
  int bn = t & 63, bk0 = (t >> 6) * 8;
  int fr = lane & 15, fh = (lane >> 4) * 8;

  const f32x4 fzero = {0.f, 0.f, 0.f, 0.f};
  f32x4 acc[2] = {fzero, fzero};

  short8 av, bv;
  auto loadA = [&](int k0) {
    if (t < 128) {
      const float* p = attn + (size_t)(m0 + ar) * 512 + k0 + ac;
      av = cvt8(*(const f32x4*)p, *(const f32x4*)(p + 4));
    }
  };
  auto loadB = [&](int k0) {
    bv = *(const short8*)(Htb + (size_t)(n0 + bn) * 512 + k0 + bk0);
  };

  loadA(0); loadB(0);
  for (int k0 = 0; k0 < 512; k0 += 32) {
    if (k0) __syncthreads();
    if (t < 128) *(short8*)&As[ar][ac] = av;
    *(short8*)&Bs[bn][bk0] = bv;
    __syncthreads();
    short8 a0 = *(const short8*)&As[wm * 16 + fr][fh];
    short8 b0 = *(const short8*)&Bs[wn * 32 + fr][fh];
    short8 b1 = *(const short8*)&Bs[wn * 32 + 16 + fr][fh];
    if (k0 + 32 < 512) { loadA(k0 + 32); loadB(k0 + 32); }
    acc[0] = __builtin_amdgcn_mfma_f32_16x16x32_bf16(a0, b0, acc[0], 0, 0, 0);
    acc[1] = __builtin_amdgcn_mfma_f32_16x16x32_bf16(a0, b1, acc[1], 0, 0, 0);
  }

  int row0 = m0 + wm * 16 + ((lane >> 4) << 2);
#pragma unroll
  for (int qn = 0; qn < 2; ++qn) {
    int col = n0 + wn * 32 + qn * 16 + (lane & 15);
#pragma unroll
    for (int j = 0; j < 4; ++j) {
      float v = acc[qn][j] + G[(size_t)(row0 + j) * 512 + col];
      float e = __builtin_amdgcn_exp2f(v * TANH_SCALE);
      v = fmaf(-2.0f, __builtin_amdgcn_rcpf(e + 1.0f), 1.0f);
      out[(size_t)(row0 + j) * 512 + col] = v;
    }
  }
}

// ---------------------------------------------------------------------------
// Fused logits+softmax, g-split across waves (no F duplication).
// grid = B*T/2 = 512 blocks (XCD-swizzled) -> 2 blocks/CU = 8 waves/SIMD.
// Block = 2 t-rows x 512 s, 1024 thr (16 waves). Wave (gh, sc): g-half
// gh*32..gh*32+31 for BOTH rows, s-chunk sc. Partials combined in LDS.
// Ftp BF16-packed [b][g][s][8]: one dwordx4 per lane per 8 d.
// ---------------------------------------------------------------------------
__global__ __launch_bounds__(1024) void logits_softmax_kernel(
    const float* __restrict__ E, const u16* __restrict__ Ftp,
    const float* __restrict__ qw, const float* __restrict__ qb,
    float* __restrict__ attn) {
  int bid = blockIdx.x;
  int logical = ((bid & 7) << 6) | (bid >> 3);  // 64 blocks/batch per XCD
  int bt0 = logical * 2;
  int b = logical >> 6;                          // == bid & 7
  int tid = threadIdx.x;
  int lane = tid & 63;
  int wv = __builtin_amdgcn_readfirstlane(tid >> 6);  // 0..15
  int gh = wv >> 3;        // g-half 0/1
  int sc = wv & 7;         // s-chunk
  int s = sc * 64 + lane;

  float qsum = 0.f;
#pragma unroll
  for (int i = 0; i < 8; ++i) qsum += qw[lane + 64 * i];
#pragma unroll
  for (int off = 32; off > 0; off >>= 1) qsum += __shfl_xor(qsum, off, 64);
  float base = qsum + qb[0];

  // Ftp[b][g][s][8] bf16; per-g stride = 8192 B = 512 u32x4.
  const u32x4* Fp = (const u32x4*)(Ftp + (size_t)b * 262144 + (size_t)s * 8);
  const float* Et0 = E + (size_t)bt0 * 512;
  const float* Et1 = Et0 + 512;

  float a0A = 0.f, a0B = 0.f, a1A = 0.f, a1B = 0.f;

  auto quad = [&](const f32x4& e, const f32x4& fc, const f32x4& q4, float& acc) {
    float x0 = fmaf(e[0], fc[0], 1.f), x1 = fmaf(e[1], fc[1], 1.f);
    float x2 = fmaf(e[2], fc[2], 1.f), x3 = fmaf(e[3], fc[3], 1.f);
    float dA = x0 * x1, dB = x2 * x3;
    float nA = fmaf(q4[0], x1, q4[1] * x0);
    float nB = fmaf(q4[2], x3, q4[3] * x2);
    float N = fmaf(nA, dB, nB * dA);
    acc = fmaf(N, __builtin_amdgcn_rcpf(dA * dB), acc);
  };

  int gbase = gh * 32;
#pragma unroll 2
  for (int gg = 0; gg < 32; ++gg) {
    int g = gbase + gg;
    u32x4 w = Fp[(size_t)g * 512];
    f32x4 f0, f1;
    f0[0] = bflo2f(w[0]); f0[1] = bfhi2f(w[0]);
    f0[2] = bflo2f(w[1]); f0[3] = bfhi2f(w[1]);
    f1[0] = bflo2f(w[2]); f1[1] = bfhi2f(w[2]);
    f1[2] = bflo2f(w[3]); f1[3] = bfhi2f(w[3]);
    f32x4 q0 = *(const f32x4*)(qw + g * 8);
    f32x4 q1 = *(const f32x4*)(qw + g * 8 + 4);
    f32x4 e00 = *(const f32x4*)(Et0 + g * 8);
    f32x4 e01 = *(const f32x4*)(Et0 + g * 8 + 4);
    f32x4 e10 = *(const f32x4*)(Et1 + g * 8);
    f32x4 e11 = *(const f32x4*)(Et1 + g * 8 + 4);
    quad(e00, f0, q0, a0A);
    quad(e01, f1, q1, a0B);
    quad(e10, f0, q0, a1A);
    quad(e11, f1, q1, a1B);
  }

  __shared__ float part[2][2][512];   // [gh][row][s]
  part[gh][0][s] = a0A + a0B;
  part[gh][1][s] = a1A + a1B;
  __syncthreads();

  // combine + softmax: thread -> (r = tid>>9, ss = tid&511)
  int r = tid >> 9;
  int ss = tid & 511;
  float l = fmaf(-2.f, part[0][r][ss] + part[1][r][ss], base);

  __shared__ float rmax[2][8], rsum[2][8];
  int scc = (tid >> 6) & 7;
  float m = l;
#pragma unroll
  for (int off = 32; off > 0; off >>= 1) m = fmaxf(m, __shfl_xor(m, off, 64));
  if (lane == 0) rmax[r][scc] = m;
  __syncthreads();
  float M = rmax[r][0];
#pragma unroll
  for (int i = 1; i < 8; ++i) M = fmaxf(M, rmax[r][i]);
  float ex = __builtin_amdgcn_exp2f((l - M) * LOG2E);
  float sv = ex;
#pragma unroll
  for (int off = 32; off > 0; off >>= 1) sv += __shfl_xor(sv, off, 64);
  if (lane == 0) rsum[r][scc] = sv;
  __syncthreads();
  float S = 0.f;
#pragma unroll
  for (int i = 0; i < 8; ++i) S += rsum[r][i];
  attn[(size_t)(bt0 + r) * 512 + ss] = ex * __builtin_amdgcn_rcpf(S);
}

extern "C" void kernel_launch(void* const* d_in, const int* in_sizes, int n_in,
                              void* d_out, int out_size, void* d_ws, size_t ws_size,
                              hipStream_t stream) {
  const float* output  = (const float*)d_in[0];  // [B,T,D]
  const float* context = (const float*)d_in[1];  // [B,S,C]
  const float* dec_w   = (const float*)d_in[2];  // [D,D]
  const float* dec_b   = (const float*)d_in[3];
  const float* attn_w  = (const float*)d_in[4];  // [C,D]
  const float* attn_b  = (const float*)d_in[5];
  const float* qw      = (const float*)d_in[6];  // [D,1]
  const float* qb      = (const float*)d_in[7];  // [1]
  const float* out_w   = (const float*)d_in[8];  // [1024,512]
  const float* out_b   = (const float*)d_in[9];

  float* out_p  = (float*)d_out;                     // [B,T,D]
  float* attn_p = out_p + (size_t)BB * TT_DIM * DD;  // [B,T,S]

  char* p = (char*)d_ws;
  float* E   = (float*)p; p += (size_t)BB * TT_DIM * DD * 4;  // 2MB
  u16* Ftp   = (u16*)p;   p += (size_t)BB * SS * DD * 2;      // 4MB packed^T bf16
  float* G   = (float*)p; p += (size_t)BB * TT_DIM * DD * 4;  // 2MB
  u16* Ht    = (u16*)p;   p += (size_t)BB * SS * DD * 2;      // 4MB bf16 ^T

  ef_gemm<<<dim3(80, 8), 256, 0, stream>>>(output, context, dec_w, attn_w,
                                           out_w, dec_b, attn_b, out_b,
                                           E, Ftp, G, Ht);
  logits_softmax_kernel<<<dim3(BB * TT_DIM / 2), 1024, 0, stream>>>(
      E, Ftp, qw, qb, attn_p);
  final_gemm<<<dim3(32, 8), 256, 0, stream>>>(attn_p, Ht, G, out_p);
}

// Round 15
// 60.227 us; speedup vs baseline: 1.2505x; 1.0563x over previous
//
#include <hip/hip_runtime.h>
#include <hip/hip_bf16.h>

#define BB 8
#define TT_DIM 128
#define SS 512
#define DD 512
#define TANH_SCALE 2.885390081777927f   // 2*log2(e)
#define LOG2E 1.4426950408889634f

typedef unsigned short u16;
typedef unsigned int u32;
typedef short short8 __attribute__((ext_vector_type(8)));
typedef short short4v __attribute__((ext_vector_type(4)));
typedef float f32x4 __attribute__((ext_vector_type(4)));
typedef unsigned int u32x4 __attribute__((ext_vector_type(4)));

__device__ __forceinline__ u16 f2bf(float f) {
  __hip_bfloat16 h = __float2bfloat16(f);
  return __builtin_bit_cast(u16, h);
}
__device__ __forceinline__ float bfhi2f(u32 w) {
  return __builtin_bit_cast(float, w & 0xFFFF0000u);
}
__device__ __forceinline__ float bflo2f(u32 w) {
  return __builtin_bit_cast(float, w << 16);
}
__device__ __forceinline__ short8 cvt8(f32x4 a, f32x4 b) {
  short8 o;
  o[0] = (short)f2bf(a[0]); o[1] = (short)f2bf(a[1]);
  o[2] = (short)f2bf(a[2]); o[3] = (short)f2bf(a[3]);
  o[4] = (short)f2bf(b[0]); o[5] = (short)f2bf(b[1]);
  o[6] = (short)f2bf(b[2]); o[7] = (short)f2bf(b[3]);
  return o;
}

// ---------------------------------------------------------------------------
// Fused dual-GEMM (unchanged from R14).
// bx<16:   A=output:  E=exp(2*(A@dec_w+dec_b)), G=A@out_w2+out_b
// bx>=16:  A=context: Ftp=exp(2*(A@attn_w+attn_b)) packed^T bf16,
//                     Ht=(A@out_w1)^T bf16
// ---------------------------------------------------------------------------
__global__ __launch_bounds__(256) void ef_gemm(
    const float* __restrict__ output, const float* __restrict__ context,
    const float* __restrict__ dec_w, const float* __restrict__ attn_w,
    const float* __restrict__ out_w,
    const float* __restrict__ dec_b, const float* __restrict__ attn_b,
    const float* __restrict__ out_b,
    float* __restrict__ E, u16* __restrict__ Ftp,
    float* __restrict__ G, u16* __restrict__ Ht) {
  int bx = blockIdx.x;
  bool isF = bx >= 16;
  const float* A  = isF ? context : output;
  const float* B1 = isF ? attn_w : dec_w;
  const float* B2 = isF ? out_w : out_w + 512 * 512;
  const float* bias1 = isF ? attn_b : dec_b;
  int m0 = (isF ? bx - 16 : bx) * 64;
  int n0 = blockIdx.y * 64;

  __shared__ u16 As[64][40];
  __shared__ u16 Bs1[64][40];
  __shared__ u16 Bs2[64][40];
  int t = threadIdx.x;
  int lane = t & 63, wid = t >> 6, wm = wid >> 1, wn = wid & 1;
  int ar = t >> 2, ac = (t & 3) * 8;
  int bn = t & 63, bk0 = (t >> 6) * 8;
  int fr = lane & 15, fh = (lane >> 4) * 8;

  const f32x4 fzero = {0.f, 0.f, 0.f, 0.f};
  f32x4 acc1[2][2], acc2[2][2];
#pragma unroll
  for (int i = 0; i < 2; ++i)
#pragma unroll
    for (int j = 0; j < 2; ++j) { acc1[i][j] = fzero; acc2[i][j] = fzero; }

  short8 av, bv1, bv2;
  auto loadA = [&](int k0) {
    const float* p = A + (size_t)(m0 + ar) * 512 + k0 + ac;
    av = cvt8(*(const f32x4*)p, *(const f32x4*)(p + 4));
  };
  auto loadB = [&](const float* B, int k0, short8& dst) {
    const float* p = B + (size_t)(k0 + bk0) * 512 + n0 + bn;
#pragma unroll
    for (int i = 0; i < 8; ++i) dst[i] = (short)f2bf(p[(size_t)i * 512]);
  };

  loadA(0); loadB(B1, 0, bv1); loadB(B2, 0, bv2);
  for (int k0 = 0; k0 < 512; k0 += 32) {
    if (k0) __syncthreads();
    *(short8*)&As[ar][ac] = av;
    *(short8*)&Bs1[bn][bk0] = bv1;
    *(short8*)&Bs2[bn][bk0] = bv2;
    __syncthreads();
    short8 a0 = *(const short8*)&As[wm * 32 + fr][fh];
    short8 a1 = *(const short8*)&As[wm * 32 + 16 + fr][fh];
    short8 p0 = *(const short8*)&Bs1[wn * 32 + fr][fh];
    short8 p1 = *(const short8*)&Bs1[wn * 32 + 16 + fr][fh];
    short8 r0 = *(const short8*)&Bs2[wn * 32 + fr][fh];
    short8 r1 = *(const short8*)&Bs2[wn * 32 + 16 + fr][fh];
    if (k0 + 32 < 512) { loadA(k0 + 32); loadB(B1, k0 + 32, bv1); loadB(B2, k0 + 32, bv2); }
    acc1[0][0] = __builtin_amdgcn_mfma_f32_16x16x32_bf16(a0, p0, acc1[0][0], 0, 0, 0);
    acc1[0][1] = __builtin_amdgcn_mfma_f32_16x16x32_bf16(a0, p1, acc1[0][1], 0, 0, 0);
    acc1[1][0] = __builtin_amdgcn_mfma_f32_16x16x32_bf16(a1, p0, acc1[1][0], 0, 0, 0);
    acc1[1][1] = __builtin_amdgcn_mfma_f32_16x16x32_bf16(a1, p1, acc1[1][1], 0, 0, 0);
    acc2[0][0] = __builtin_amdgcn_mfma_f32_16x16x32_bf16(a0, r0, acc2[0][0], 0, 0, 0);
    acc2[0][1] = __builtin_amdgcn_mfma_f32_16x16x32_bf16(a0, r1, acc2[0][1], 0, 0, 0);
    acc2[1][0] = __builtin_amdgcn_mfma_f32_16x16x32_bf16(a1, r0, acc2[1][0], 0, 0, 0);
    acc2[1][1] = __builtin_amdgcn_mfma_f32_16x16x32_bf16(a1, r1, acc2[1][1], 0, 0, 0);
  }

  // C/D layout (m89): col = lane&15, row = (lane>>4)*4 + j
#pragma unroll
  for (int qa = 0; qa < 2; ++qa) {
    int rbase = wm * 32 + qa * 16 + ((lane >> 4) << 2);
#pragma unroll
    for (int qn = 0; qn < 2; ++qn) {
      int col = n0 + wn * 32 + qn * 16 + (lane & 15);
      float b1v = bias1[col];
      int bb = m0 >> 9;
      int srow = (m0 & 511) + rbase;
      if (isF) {
        size_t fbase = ((size_t)bb * 64 + (col >> 3)) * 4096 + (size_t)(col & 7);
        short4v ho;
#pragma unroll
        for (int j = 0; j < 4; ++j) {
          float v1 = __builtin_amdgcn_exp2f((acc1[qa][qn][j] + b1v) * TANH_SCALE);
          Ftp[fbase + (size_t)(srow + j) * 8] = f2bf(v1);
          ho[j] = (short)f2bf(acc2[qa][qn][j]);
        }
        *(short4v*)&Ht[((size_t)bb * 512 + col) * 512 + srow] = ho;
      } else {
        float b2v = out_b[col];
#pragma unroll
        for (int j = 0; j < 4; ++j) {
          float v1 = __builtin_amdgcn_exp2f((acc1[qa][qn][j] + b1v) * TANH_SCALE);
          E[(size_t)(m0 + rbase + j) * 512 + col] = v1;
          G[(size_t)(m0 + rbase + j) * 512 + col] = acc2[qa][qn][j] + b2v;
        }
      }
    }
  }
}

// ---------------------------------------------------------------------------
// final: out = tanh(attn_bf @ Ht^T + G). 32x64 tile, grid (32,8).
// A now bf16 (from logits) -> pure short8 staging.
// ---------------------------------------------------------------------------
__global__ __launch_bounds__(256) void final_gemm(
    const u16* __restrict__ attn_bf, const u16* __restrict__ Ht,
    const float* __restrict__ G, float* __restrict__ out) {
  int m0 = blockIdx.x * 32, n0 = blockIdx.y * 64;
  int b = m0 >> 7;   // T = 128
  const u16* Htb = Ht + (size_t)b * 512 * 512;

  __shared__ u16 As[32][40];
  __shared__ u16 Bs[64][40];
  int t = threadIdx.x;
  int lane = t & 63, wid = t >> 6, wm = wid >> 1, wn = wid & 1;
  int ar = t >> 2, ac = (t & 3) * 8;
  int bn = t & 63, bk0 = (t >> 6) * 8;
  int fr = lane & 15, fh = (lane >> 4) * 8;

  const f32x4 fzero = {0.f, 0.f, 0.f, 0.f};
  f32x4 acc[2] = {fzero, fzero};

  short8 av, bv;
  auto loadA = [&](int k0) {
    if (t < 128)
      av = *(const short8*)(attn_bf + (size_t)(m0 + ar) * 512 + k0 + ac);
  };
  auto loadB = [&](int k0) {
    bv = *(const short8*)(Htb + (size_t)(n0 + bn) * 512 + k0 + bk0);
  };

  loadA(0); loadB(0);
  for (int k0 = 0; k0 < 512; k0 += 32) {
    if (k0) __syncthreads();
    if (t < 128) *(short8*)&As[ar][ac] = av;
    *(short8*)&Bs[bn][bk0] = bv;
    __syncthreads();
    short8 a0 = *(const short8*)&As[wm * 16 + fr][fh];
    short8 b0 = *(const short8*)&Bs[wn * 32 + fr][fh];
    short8 b1 = *(const short8*)&Bs[wn * 32 + 16 + fr][fh];
    if (k0 + 32 < 512) { loadA(k0 + 32); loadB(k0 + 32); }
    acc[0] = __builtin_amdgcn_mfma_f32_16x16x32_bf16(a0, b0, acc[0], 0, 0, 0);
    acc[1] = __builtin_amdgcn_mfma_f32_16x16x32_bf16(a0, b1, acc[1], 0, 0, 0);
  }

  int row0 = m0 + wm * 16 + ((lane >> 4) << 2);
#pragma unroll
  for (int qn = 0; qn < 2; ++qn) {
    int col = n0 + wn * 32 + qn * 16 + (lane & 15);
#pragma unroll
    for (int j = 0; j < 4; ++j) {
      float v = acc[qn][j] + G[(size_t)(row0 + j) * 512 + col];
      float e = __builtin_amdgcn_exp2f(v * TANH_SCALE);
      v = fmaf(-2.0f, __builtin_amdgcn_rcpf(e + 1.0f), 1.0f);
      out[(size_t)(row0 + j) * 512 + col] = v;
    }
  }
}

// ---------------------------------------------------------------------------
// Fused logits+softmax: 4 t-rows x g-split.
// grid = B*T/4 = 256 (XCD-swizzled), block = 1024 (16 waves).
// Wave (gh, sc): rows bt0..bt0+3, g in [gh*32, gh*32+32), s-chunk sc.
// F L2 traffic = 128 MB total; unpack amortized over 8 quads/g.
// Partials -> 16KB LDS -> combine+softmax by 4-wave row groups.
// Emits fp32 attn (output) + bf16 attn (for final).
// ---------------------------------------------------------------------------
__global__ __launch_bounds__(1024) void logits_softmax_kernel(
    const float* __restrict__ E, const u16* __restrict__ Ftp,
    const float* __restrict__ qw, const float* __restrict__ qb,
    float* __restrict__ attn, u16* __restrict__ attn_bf) {
  int bid = blockIdx.x;
  int logical = ((bid & 7) << 5) | (bid >> 3);  // batch = bid&7 per XCD
  int bt0 = logical * 4;
  int b = logical >> 5;                          // == bid & 7
  int tid = threadIdx.x;
  int lane = tid & 63;
  int wv = __builtin_amdgcn_readfirstlane(tid >> 6);  // 0..15
  int gh = wv >> 3;        // g-half
  int sc = wv & 7;         // s-chunk
  int s = sc * 64 + lane;

  float qsum = 0.f;
#pragma unroll
  for (int i = 0; i < 8; ++i) qsum += qw[lane + 64 * i];
#pragma unroll
  for (int off = 32; off > 0; off >>= 1) qsum += __shfl_xor(qsum, off, 64);
  float base = qsum + qb[0];

  const u32x4* Fp = (const u32x4*)(Ftp + (size_t)b * 262144 + (size_t)s * 8);
  const float* Et0 = E + (size_t)bt0 * 512;
  const float* Et1 = Et0 + 512;
  const float* Et2 = Et0 + 1024;
  const float* Et3 = Et0 + 1536;

  float a0A = 0.f, a0B = 0.f, a1A = 0.f, a1B = 0.f;
  float a2A = 0.f, a2B = 0.f, a3A = 0.f, a3B = 0.f;

  auto quad = [&](const f32x4& e, const f32x4& fc, const f32x4& q4, float& acc) {
    float x0 = fmaf(e[0], fc[0], 1.f), x1 = fmaf(e[1], fc[1], 1.f);
    float x2 = fmaf(e[2], fc[2], 1.f), x3 = fmaf(e[3], fc[3], 1.f);
    float dA = x0 * x1, dB = x2 * x3;
    float nA = fmaf(q4[0], x1, q4[1] * x0);
    float nB = fmaf(q4[2], x3, q4[3] * x2);
    float N = fmaf(nA, dB, nB * dA);
    acc = fmaf(N, __builtin_amdgcn_rcpf(dA * dB), acc);
  };

  int gbase = gh * 32;
#pragma unroll 2
  for (int gg = 0; gg < 32; ++gg) {
    int g = gbase + gg;
    u32x4 w = Fp[(size_t)g * 512];   // per-g stride = 8192 B = 512 u32x4
    f32x4 f0, f1;
    f0[0] = bflo2f(w[0]); f0[1] = bfhi2f(w[0]);
    f0[2] = bflo2f(w[1]); f0[3] = bfhi2f(w[1]);
    f1[0] = bflo2f(w[2]); f1[1] = bfhi2f(w[2]);
    f1[2] = bflo2f(w[3]); f1[3] = bfhi2f(w[3]);
    f32x4 q0 = *(const f32x4*)(qw + g * 8);
    f32x4 q1 = *(const f32x4*)(qw + g * 8 + 4);
    quad(*(const f32x4*)(Et0 + g * 8),     f0, q0, a0A);
    quad(*(const f32x4*)(Et0 + g * 8 + 4), f1, q1, a0B);
    quad(*(const f32x4*)(Et1 + g * 8),     f0, q0, a1A);
    quad(*(const f32x4*)(Et1 + g * 8 + 4), f1, q1, a1B);
    quad(*(const f32x4*)(Et2 + g * 8),     f0, q0, a2A);
    quad(*(const f32x4*)(Et2 + g * 8 + 4), f1, q1, a2B);
    quad(*(const f32x4*)(Et3 + g * 8),     f0, q0, a3A);
    quad(*(const f32x4*)(Et3 + g * 8 + 4), f1, q1, a3B);
  }

  __shared__ float part[2][4][512];   // [gh][row][s]  16 KB
  part[gh][0][s] = a0A + a0B;
  part[gh][1][s] = a1A + a1B;
  part[gh][2][s] = a2A + a2B;
  part[gh][3][s] = a3A + a3B;
  __syncthreads();

  // combine + softmax: row r = tid>>8 (0..3), ss = tid&255 and ss+256.
  int r = tid >> 8;
  int ss = tid & 255;
  int wir = (tid >> 6) & 3;   // wave index within row group
  float l0 = fmaf(-2.f, part[0][r][ss] + part[1][r][ss], base);
  float l1 = fmaf(-2.f, part[0][r][ss + 256] + part[1][r][ss + 256], base);

  __shared__ float rmax[4][4], rsum[4][4];
  float m = fmaxf(l0, l1);
#pragma unroll
  for (int off = 32; off > 0; off >>= 1) m = fmaxf(m, __shfl_xor(m, off, 64));
  if (lane == 0) rmax[r][wir] = m;
  __syncthreads();
  float M = fmaxf(fmaxf(rmax[r][0], rmax[r][1]), fmaxf(rmax[r][2], rmax[r][3]));
  float ex0 = __builtin_amdgcn_exp2f((l0 - M) * LOG2E);
  float ex1 = __builtin_amdgcn_exp2f((l1 - M) * LOG2E);
  float sv = ex0 + ex1;
#pragma unroll
  for (int off = 32; off > 0; off >>= 1) sv += __shfl_xor(sv, off, 64);
  if (lane == 0) rsum[r][wir] = sv;
  __syncthreads();
  float S = (rsum[r][0] + rsum[r][1]) + (rsum[r][2] + rsum[r][3]);
  float inv = __builtin_amdgcn_rcpf(S);
  float o0 = ex0 * inv, o1 = ex1 * inv;
  size_t i0 = (size_t)(bt0 + r) * 512 + ss;
  attn[i0] = o0;
  attn[i0 + 256] = o1;
  attn_bf[i0] = f2bf(o0);
  attn_bf[i0 + 256] = f2bf(o1);
}

extern "C" void kernel_launch(void* const* d_in, const int* in_sizes, int n_in,
                              void* d_out, int out_size, void* d_ws, size_t ws_size,
                              hipStream_t stream) {
  const float* output  = (const float*)d_in[0];  // [B,T,D]
  const float* context = (const float*)d_in[1];  // [B,S,C]
  const float* dec_w   = (const float*)d_in[2];  // [D,D]
  const float* dec_b   = (const float*)d_in[3];
  const float* attn_w  = (const float*)d_in[4];  // [C,D]
  const float* attn_b  = (const float*)d_in[5];
  const float* qw      = (const float*)d_in[6];  // [D,1]
  const float* qb      = (const float*)d_in[7];  // [1]
  const float* out_w   = (const float*)d_in[8];  // [1024,512]
  const float* out_b   = (const float*)d_in[9];

  float* out_p  = (float*)d_out;                     // [B,T,D]
  float* attn_p = out_p + (size_t)BB * TT_DIM * DD;  // [B,T,S]

  char* p = (char*)d_ws;
  float* E    = (float*)p; p += (size_t)BB * TT_DIM * DD * 4;  // 2MB
  u16* Ftp    = (u16*)p;   p += (size_t)BB * SS * DD * 2;      // 4MB packed^T bf16
  float* G    = (float*)p; p += (size_t)BB * TT_DIM * DD * 4;  // 2MB
  u16* Ht     = (u16*)p;   p += (size_t)BB * SS * DD * 2;      // 4MB bf16 ^T
  u16* attnbf = (u16*)p;   p += (size_t)BB * TT_DIM * SS * 2;  // 1MB

  ef_gemm<<<dim3(80, 8), 256, 0, stream>>>(output, context, dec_w, attn_w,
                                           out_w, dec_b, attn_b, out_b,
                                           E, Ftp, G, Ht);
  logits_softmax_kernel<<<dim3(BB * TT_DIM / 4), 1024, 0, stream>>>(
      E, Ftp, qw, qb, attn_p, attnbf);
  final_gemm<<<dim3(32, 8), 256, 0, stream>>>(attnbf, Ht, G, out_p);
}

// Round 17
// 59.090 us; speedup vs baseline: 1.2746x; 1.0192x over previous
//
#include <hip/hip_runtime.h>
#include <hip/hip_bf16.h>

#define BB 8
#define TT_DIM 128
#define SS 512
#define DD 512
#define TANH_SCALE 2.885390081777927f   // 2*log2(e)
#define LOG2E 1.4426950408889634f

typedef unsigned short u16;
typedef unsigned int u32;
typedef short short8 __attribute__((ext_vector_type(8)));
typedef short short4v __attribute__((ext_vector_type(4)));
typedef float f32x2 __attribute__((ext_vector_type(2)));
typedef float f32x4 __attribute__((ext_vector_type(4)));
typedef unsigned int u32x4 __attribute__((ext_vector_type(4)));

__device__ __forceinline__ u16 f2bf(float f) {
  __hip_bfloat16 h = __float2bfloat16(f);
  return __builtin_bit_cast(u16, h);
}
__device__ __forceinline__ float bfhi2f(u32 w) {
  return __builtin_bit_cast(float, w & 0xFFFF0000u);
}
__device__ __forceinline__ float bflo2f(u32 w) {
  return __builtin_bit_cast(float, w << 16);
}
__device__ __forceinline__ f32x2 vlo(f32x4 v) {
  return __builtin_shufflevector(v, v, 0, 1);
}
__device__ __forceinline__ f32x2 vhi(f32x4 v) {
  return __builtin_shufflevector(v, v, 2, 3);
}
__device__ __forceinline__ f32x2 splat2(float x) {
  f32x2 v; v.x = x; v.y = x; return v;
}
__device__ __forceinline__ short8 cvt8(f32x4 a, f32x4 b) {
  short8 o;
  o[0] = (short)f2bf(a[0]); o[1] = (short)f2bf(a[1]);
  o[2] = (short)f2bf(a[2]); o[3] = (short)f2bf(a[3]);
  o[4] = (short)f2bf(b[0]); o[5] = (short)f2bf(b[1]);
  o[6] = (short)f2bf(b[2]); o[7] = (short)f2bf(b[3]);
  return o;
}

// ---------------------------------------------------------------------------
// Fused dual-GEMM (R14 structure; E written row-pair interleaved).
// bx<16:   A=output:  E2=exp(2*(A@dec_w+dec_b)) interleaved [t>>1][d][t&1],
//                     G=A@out_w2+out_b
// bx>=16:  A=context: Ftp=exp(2*(A@attn_w+attn_b)) packed^T bf16,
//                     Ht=(A@out_w1)^T bf16
// ---------------------------------------------------------------------------
__global__ __launch_bounds__(256) void ef_gemm(
    const float* __restrict__ output, const float* __restrict__ context,
    const float* __restrict__ dec_w, const float* __restrict__ attn_w,
    const float* __restrict__ out_w,
    const float* __restrict__ dec_b, const float* __restrict__ attn_b,
    const float* __restrict__ out_b,
    float* __restrict__ E2, u16* __restrict__ Ftp,
    float* __restrict__ G, u16* __restrict__ Ht) {
  int bx = blockIdx.x;
  bool isF = bx >= 16;
  const float* A  = isF ? context : output;
  const float* B1 = isF ? attn_w : dec_w;
  const float* B2 = isF ? out_w : out_w + 512 * 512;
  const float* bias1 = isF ? attn_b : dec_b;
  int m0 = (isF ? bx - 16 : bx) * 64;
  int n0 = blockIdx.y * 64;

  __shared__ u16 As[64][40];
  __shared__ u16 Bs1[64][40];
  __shared__ u16 Bs2[64][40];
  int t = threadIdx.x;
  int lane = t & 63, wid = t >> 6, wm = wid >> 1, wn = wid & 1;
  int ar = t >> 2, ac = (t & 3) * 8;
  int bn = t & 63, bk0 = (t >> 6) * 8;
  int fr = lane & 15, fh = (lane >> 4) * 8;

  const f32x4 fzero = {0.f, 0.f, 0.f, 0.f};
  f32x4 acc1[2][2], acc2[2][2];
#pragma unroll
  for (int i = 0; i < 2; ++i)
#pragma unroll
    for (int j = 0; j < 2; ++j) { acc1[i][j] = fzero; acc2[i][j] = fzero; }

  short8 av, bv1, bv2;
  auto loadA = [&](int k0) {
    const float* p = A + (size_t)(m0 + ar) * 512 + k0 + ac;
    av = cvt8(*(const f32x4*)p, *(const f32x4*)(p + 4));
  };
  auto loadB = [&](const float* B, int k0, short8& dst) {
    const float* p = B + (size_t)(k0 + bk0) * 512 + n0 + bn;
#pragma unroll
    for (int i = 0; i < 8; ++i) dst[i] = (short)f2bf(p[(size_t)i * 512]);
  };

  loadA(0); loadB(B1, 0, bv1); loadB(B2, 0, bv2);
  for (int k0 = 0; k0 < 512; k0 += 32) {
    if (k0) __syncthreads();
    *(short8*)&As[ar][ac] = av;
    *(short8*)&Bs1[bn][bk0] = bv1;
    *(short8*)&Bs2[bn][bk0] = bv2;
    __syncthreads();
    short8 a0 = *(const short8*)&As[wm * 32 + fr][fh];
    short8 a1 = *(const short8*)&As[wm * 32 + 16 + fr][fh];
    short8 p0 = *(const short8*)&Bs1[wn * 32 + fr][fh];
    short8 p1 = *(const short8*)&Bs1[wn * 32 + 16 + fr][fh];
    short8 r0 = *(const short8*)&Bs2[wn * 32 + fr][fh];
    short8 r1 = *(const short8*)&Bs2[wn * 32 + 16 + fr][fh];
    if (k0 + 32 < 512) { loadA(k0 + 32); loadB(B1, k0 + 32, bv1); loadB(B2, k0 + 32, bv2); }
    acc1[0][0] = __builtin_amdgcn_mfma_f32_16x16x32_bf16(a0, p0, acc1[0][0], 0, 0, 0);
    acc1[0][1] = __builtin_amdgcn_mfma_f32_16x16x32_bf16(a0, p1, acc1[0][1], 0, 0, 0);
    acc1[1][0] = __builtin_amdgcn_mfma_f32_16x16x32_bf16(a1, p0, acc1[1][0], 0, 0, 0);
    acc1[1][1] = __builtin_amdgcn_mfma_f32_16x16x32_bf16(a1, p1, acc1[1][1], 0, 0, 0);
    acc2[0][0] = __builtin_amdgcn_mfma_f32_16x16x32_bf16(a0, r0, acc2[0][0], 0, 0, 0);
    acc2[0][1] = __builtin_amdgcn_mfma_f32_16x16x32_bf16(a0, r1, acc2[0][1], 0, 0, 0);
    acc2[1][0] = __builtin_amdgcn_mfma_f32_16x16x32_bf16(a1, r0, acc2[1][0], 0, 0, 0);
    acc2[1][1] = __builtin_amdgcn_mfma_f32_16x16x32_bf16(a1, r1, acc2[1][1], 0, 0, 0);
  }

  // C/D layout (m89): col = lane&15, row = (lane>>4)*4 + j
#pragma unroll
  for (int qa = 0; qa < 2; ++qa) {
    int rbase = wm * 32 + qa * 16 + ((lane >> 4) << 2);
#pragma unroll
    for (int qn = 0; qn < 2; ++qn) {
      int col = n0 + wn * 32 + qn * 16 + (lane & 15);
      float b1v = bias1[col];
      int bb = m0 >> 9;
      int srow = (m0 & 511) + rbase;
      if (isF) {
        size_t fbase = ((size_t)bb * 64 + (col >> 3)) * 4096 + (size_t)(col & 7);
        short4v ho;
#pragma unroll
        for (int j = 0; j < 4; ++j) {
          float v1 = __builtin_amdgcn_exp2f((acc1[qa][qn][j] + b1v) * TANH_SCALE);
          Ftp[fbase + (size_t)(srow + j) * 8] = f2bf(v1);
          ho[j] = (short)f2bf(acc2[qa][qn][j]);
        }
        *(short4v*)&Ht[((size_t)bb * 512 + col) * 512 + srow] = ho;
      } else {
        float b2v = out_b[col];
#pragma unroll
        for (int j = 0; j < 4; ++j) {
          float v1 = __builtin_amdgcn_exp2f((acc1[qa][qn][j] + b1v) * TANH_SCALE);
          int row = m0 + rbase + j;
          E2[(((size_t)row >> 1) * 512 + col) * 2 + (row & 1)] = v1;
          G[(size_t)row * 512 + col] = acc2[qa][qn][j] + b2v;
        }
      }
    }
  }
}

// ---------------------------------------------------------------------------
// final: out = tanh(attn_bf @ Ht^T + G). 32x64 tile, grid (32,8). (R15)
// ---------------------------------------------------------------------------
__global__ __launch_bounds__(256) void final_gemm(
    const u16* __restrict__ attn_bf, const u16* __restrict__ Ht,
    const float* __restrict__ G, float* __restrict__ out) {
  int m0 = blockIdx.x * 32, n0 = blockIdx.y * 64;
  int b = m0 >> 7;   // T = 128
  const u16* Htb = Ht + (size_t)b * 512 * 512;

  __shared__ u16 As[32][40];
  __shared__ u16 Bs[64][40];
  int t = threadIdx.x;
  int lane = t & 63, wid = t >> 6, wm = wid >> 1, wn = wid & 1;
  int ar = t >> 2, ac = (t & 3) * 8;
  int bn = t & 63, bk0 = (t >> 6) * 8;
  int fr = lane & 15, fh = (lane >> 4) * 8;

  const f32x4 fzero = {0.f, 0.f, 0.f, 0.f};
  f32x4 acc[2] = {fzero, fzero};

  short8 av, bv;
  auto loadA = [&](int k0) {
    if (t < 128)
      av = *(const short8*)(attn_bf + (size_t)(m0 + ar) * 512 + k0 + ac);
  };
  auto loadB = [&](int k0) {
    bv = *(const short8*)(Htb + (size_t)(n0 + bn) * 512 + k0 + bk0);
  };

  loadA(0); loadB(0);
  for (int k0 = 0; k0 < 512; k0 += 32) {
    if (k0) __syncthreads();
    if (t < 128) *(short8*)&As[ar][ac] = av;
    *(short8*)&Bs[bn][bk0] = bv;
    __syncthreads();
    short8 a0 = *(const short8*)&As[wm * 16 + fr][fh];
    short8 b0 = *(const short8*)&Bs[wn * 32 + fr][fh];
    short8 b1 = *(const short8*)&Bs[wn * 32 + 16 + fr][fh];
    if (k0 + 32 < 512) { loadA(k0 + 32); loadB(k0 + 32); }
    acc[0] = __builtin_amdgcn_mfma_f32_16x16x32_bf16(a0, b0, acc[0], 0, 0, 0);
    acc[1] = __builtin_amdgcn_mfma_f32_16x16x32_bf16(a0, b1, acc[1], 0, 0, 0);
  }

  int row0 = m0 + wm * 16 + ((lane >> 4) << 2);
#pragma unroll
  for (int qn = 0; qn < 2; ++qn) {
    int col = n0 + wn * 32 + qn * 16 + (lane & 15);
#pragma unroll
    for (int j = 0; j < 4; ++j) {
      float v = acc[qn][j] + G[(size_t)(row0 + j) * 512 + col];
      float e = __builtin_amdgcn_exp2f(v * TANH_SCALE);
      v = fmaf(-2.0f, __builtin_amdgcn_rcpf(e + 1.0f), 1.0f);
      out[(size_t)(row0 + j) * 512 + col] = v;
    }
  }
}

// ---------------------------------------------------------------------------
// Fused logits+softmax, packed-f32 (v_pk_*) over row pairs.
// grid = B*T/4 = 256 (XCD-swizzled), block = 1024 (16 waves).
// Wave (gh, sc): rows bt0..bt0+3 as 2 pairs, g in [gh*32,+32), s-chunk sc.
// E2[(t>>1)*512+d][2]: one f32x4 load = 2 d x 2 rows, no shuffles.
// l = -2*sum(q*r) directly (softmax shift-invariant: qsum+qb dropped).
// ---------------------------------------------------------------------------
__global__ __launch_bounds__(1024) void logits_softmax_kernel(
    const float* __restrict__ E2, const u16* __restrict__ Ftp,
    const float* __restrict__ qw,
    float* __restrict__ attn, u16* __restrict__ attn_bf) {
  int bid = blockIdx.x;
  int logical = ((bid & 7) << 5) | (bid >> 3);  // batch = bid&7 per XCD
  int bt0 = logical * 4;
  int b = logical >> 5;
  int tid = threadIdx.x;
  int lane = tid & 63;
  int wv = __builtin_amdgcn_readfirstlane(tid >> 6);
  int gh = wv >> 3;
  int sc = wv & 7;
  int s = sc * 64 + lane;

  const u32x4* Fp = (const u32x4*)(Ftp + (size_t)b * 262144 + (size_t)s * 8);
  const float* E2p0 = E2 + ((size_t)(bt0 >> 1)) * 1024;   // pair0: rows bt0,bt0+1
  const float* E2p1 = E2p0 + 1024;                        // pair1

  const f32x2 one2 = {1.f, 1.f};
  f32x2 aP0A = {0.f, 0.f}, aP0B = {0.f, 0.f};
  f32x2 aP1A = {0.f, 0.f}, aP1B = {0.f, 0.f};

  // quad over 4 d's for a row pair; e's are (row0,row1) pairs, f/q splatted.
  auto quadpk = [&](f32x2 e0, f32x2 e1, f32x2 e2, f32x2 e3,
                    f32x2 ff0, f32x2 ff1, f32x2 ff2, f32x2 ff3,
                    float q0, float q1, float q2, float q3, f32x2& acc) {
    f32x2 x0 = e0 * ff0 + one2, x1 = e1 * ff1 + one2;
    f32x2 x2 = e2 * ff2 + one2, x3 = e3 * ff3 + one2;
    f32x2 dA = x0 * x1, dB = x2 * x3;
    f32x2 nA = q0 * x1 + q1 * x0;
    f32x2 nB = q2 * x3 + q3 * x2;
    f32x2 N = nA * dB + nB * dA;
    f32x2 D = dA * dB;
    f32x2 r;
    r.x = __builtin_amdgcn_rcpf(D.x);
    r.y = __builtin_amdgcn_rcpf(D.y);
    acc += N * r;
  };

  int gbase = gh * 32;
#pragma unroll 2
  for (int gg = 0; gg < 32; ++gg) {
    int g = gbase + gg;
    u32x4 w = Fp[(size_t)g * 512];   // per-g stride = 8192 B = 512 u32x4
    f32x2 ff0 = splat2(bflo2f(w[0])), ff1 = splat2(bfhi2f(w[0]));
    f32x2 ff2 = splat2(bflo2f(w[1])), ff3 = splat2(bfhi2f(w[1]));
    f32x2 ff4 = splat2(bflo2f(w[2])), ff5 = splat2(bfhi2f(w[2]));
    f32x2 ff6 = splat2(bflo2f(w[3])), ff7 = splat2(bfhi2f(w[3]));
    f32x4 q0v = *(const f32x4*)(qw + g * 8);
    f32x4 q1v = *(const f32x4*)(qw + g * 8 + 4);
    // E2 pair loads: f32x4 = (d, rows 0/1) x 2
    f32x4 ea0 = *(const f32x4*)(E2p0 + g * 16);       // d0,d1
    f32x4 eb0 = *(const f32x4*)(E2p0 + g * 16 + 4);   // d2,d3
    f32x4 ec0 = *(const f32x4*)(E2p0 + g * 16 + 8);   // d4,d5
    f32x4 ed0 = *(const f32x4*)(E2p0 + g * 16 + 12);  // d6,d7
    f32x4 ea1 = *(const f32x4*)(E2p1 + g * 16);
    f32x4 eb1 = *(const f32x4*)(E2p1 + g * 16 + 4);
    f32x4 ec1 = *(const f32x4*)(E2p1 + g * 16 + 8);
    f32x4 ed1 = *(const f32x4*)(E2p1 + g * 16 + 12);
    quadpk(vlo(ea0), vhi(ea0), vlo(eb0), vhi(eb0),
           ff0, ff1, ff2, ff3, q0v[0], q0v[1], q0v[2], q0v[3], aP0A);
    quadpk(vlo(ec0), vhi(ec0), vlo(ed0), vhi(ed0),
           ff4, ff5, ff6, ff7, q1v[0], q1v[1], q1v[2], q1v[3], aP0B);
    quadpk(vlo(ea1), vhi(ea1), vlo(eb1), vhi(eb1),
           ff0, ff1, ff2, ff3, q0v[0], q0v[1], q0v[2], q0v[3], aP1A);
    quadpk(vlo(ec1), vhi(ec1), vlo(ed1), vhi(ed1),
           ff4, ff5, ff6, ff7, q1v[0], q1v[1], q1v[2], q1v[3], aP1B);
  }

  __shared__ float part[2][4][512];   // [gh][row][s]  16 KB
  part[gh][0][s] = aP0A.x + aP0B.x;
  part[gh][1][s] = aP0A.y + aP0B.y;
  part[gh][2][s] = aP1A.x + aP1B.x;
  part[gh][3][s] = aP1A.y + aP1B.y;
  __syncthreads();

  // combine + softmax: row r = tid>>8 (0..3), cols ss and ss+256.
  int r = tid >> 8;
  int ss = tid & 255;
  int wir = (tid >> 6) & 3;
  float l0 = -2.f * (part[0][r][ss] + part[1][r][ss]);
  float l1 = -2.f * (part[0][r][ss + 256] + part[1][r][ss + 256]);

  __shared__ float rmax[4][4], rsum[4][4];
  float m = fmaxf(l0, l1);
#pragma unroll
  for (int off = 32; off > 0; off >>= 1) m = fmaxf(m, __shfl_xor(m, off, 64));
  if (lane == 0) rmax[r][wir] = m;
  __syncthreads();
  float M = fmaxf(fmaxf(rmax[r][0], rmax[r][1]), fmaxf(rmax[r][2], rmax[r][3]));
  float ex0 = __builtin_amdgcn_exp2f((l0 - M) * LOG2E);
  float ex1 = __builtin_amdgcn_exp2f((l1 - M) * LOG2E);
  float sv = ex0 + ex1;
#pragma unroll
  for (int off = 32; off > 0; off >>= 1) sv += __shfl_xor(sv, off, 64);
  if (lane == 0) rsum[r][wir] = sv;
  __syncthreads();
  float S = (rsum[r][0] + rsum[r][1]) + (rsum[r][2] + rsum[r][3]);
  float inv = __builtin_amdgcn_rcpf(S);
  float o0 = ex0 * inv, o1 = ex1 * inv;
  size_t i0 = (size_t)(bt0 + r) * 512 + ss;
  attn[i0] = o0;
  attn[i0 + 256] = o1;
  attn_bf[i0] = f2bf(o0);
  attn_bf[i0 + 256] = f2bf(o1);
}

extern "C" void kernel_launch(void* const* d_in, const int* in_sizes, int n_in,
                              void* d_out, int out_size, void* d_ws, size_t ws_size,
                              hipStream_t stream) {
  const float* output  = (const float*)d_in[0];  // [B,T,D]
  const float* context = (const float*)d_in[1];  // [B,S,C]
  const float* dec_w   = (const float*)d_in[2];  // [D,D]
  const float* dec_b   = (const float*)d_in[3];
  const float* attn_w  = (const float*)d_in[4];  // [C,D]
  const float* attn_b  = (const float*)d_in[5];
  const float* qw      = (const float*)d_in[6];  // [D,1]
  const float* qb      = (const float*)d_in[7];  // [1]  (unused: softmax-invariant)
  const float* out_w   = (const float*)d_in[8];  // [1024,512]
  const float* out_b   = (const float*)d_in[9];
  (void)qb;

  float* out_p  = (float*)d_out;                     // [B,T,D]
  float* attn_p = out_p + (size_t)BB * TT_DIM * DD;  // [B,T,S]

  char* p = (char*)d_ws;
  float* E2   = (float*)p; p += (size_t)BB * TT_DIM * DD * 4;  // 2MB interleaved
  u16* Ftp    = (u16*)p;   p += (size_t)BB * SS * DD * 2;      // 4MB packed^T bf16
  float* G    = (float*)p; p += (size_t)BB * TT_DIM * DD * 4;  // 2MB
  u16* Ht     = (u16*)p;   p += (size_t)BB * SS * DD * 2;      // 4MB bf16 ^T
  u16* attnbf = (u16*)p;   p += (size_t)BB * TT_DIM * SS * 2;  // 1MB

  ef_gemm<<<dim3(80, 8), 256, 0, stream>>>(output, context, dec_w, attn_w,
                                           out_w, dec_b, attn_b, out_b,
                                           E2, Ftp, G, Ht);
  logits_softmax_kernel<<<dim3(BB * TT_DIM / 4), 1024, 0, stream>>>(
      E2, Ftp, qw, attn_p, attnbf);
  final_gemm<<<dim3(32, 8), 256, 0, stream>>>(attnbf, Ht, G, out_p);
}